// Round 6
// baseline (144.918 us; speedup 1.0000x reference)
//
#include <hip/hip_runtime.h>

// Problem constants
// B=2, L=256, D=512, H=8, Dh=64, NUM_RADIAL=64, N_SPH=9, F=576
#define NB 2
#define NL 256
#define ND 512
#define NH 8
#define NDH 64
#define NR 64
#define NS 9
#define NF 576
#define NHS 72      // NH*NS
#define WQROW 4608  // NR*NHS
#define RWIN 12     // rbf window: terms beyond 5.5*delta < 2e-7 -> negligible

__device__ __forceinline__ float block_sum(float v, float* s_red) {
    #pragma unroll
    for (int off = 32; off; off >>= 1) v += __shfl_xor(v, off, 64);
    __syncthreads();  // protect s_red from previous use
    if ((threadIdx.x & 63) == 0) s_red[threadIdx.x >> 6] = v;
    __syncthreads();
    return s_red[0] + s_red[1] + s_red[2] + s_red[3];
}

// ---------------------------------------------------------------------------
// K1: Wq[row][r*72 + h*9+s] = sum_d rp_w[(s*64+r)][h*64+d] * src[row][h*64+d]
// grid (64 rowtiles of 8, 8 heads), 256 threads.
// ---------------------------------------------------------------------------
__global__ __launch_bounds__(256) void k1_wq(const float* __restrict__ src,
                                             const float* __restrict__ rp_w,
                                             float* __restrict__ Wq) {
    int rt = blockIdx.x;   // 64 rowtiles x 8 rows
    int h  = blockIdx.y;
    int t  = threadIdx.x;
    __shared__ float s_src[8][64];   // 2 KB
    __shared__ float s_B[64 * 64];   // 16 KB, slot-swizzled rows
    int r0 = rt * 8;
    {   // stage src tile: 8 rows x 64 d, float2 per thread, coalesced
        int sr = t >> 5;
        int sc = (t & 31) * 2;
        *(float2*)&s_src[sr][sc] =
            *(const float2*)(src + (size_t)(r0 + sr) * ND + h * 64 + sc);
    }
    int ff = t & 63;        // = r index of output
    int g  = t >> 6;        // wave id 0..3 -> rows 2g, 2g+1
    int lr = t >> 2;        // loader row 0..63
    int lq = t & 3;         // loader quarter
    const float* bsrc = rp_w + h * 64;

    #pragma unroll 1
    for (int s = 0; s < NS; ++s) {
        __syncthreads();   // protect s_B (and s_src on first iter)
        #pragma unroll
        for (int i = 0; i < 4; ++i) {
            int slot = i * 4 + lq;                 // 0..15, lanes consecutive
            float4 v = *(const float4*)(bsrc + (size_t)(s * 64 + lr) * ND + slot * 4);
            int sw = slot ^ (lr & 7);
            *(float4*)&s_B[lr * 64 + sw * 4] = v;
        }
        __syncthreads();
        float a0 = 0.f, a1 = 0.f;
        #pragma unroll
        for (int d4 = 0; d4 < 16; ++d4) {
            int sw = d4 ^ (ff & 7);
            float4 bv = *(const float4*)&s_B[ff * 64 + sw * 4];
            float4 s0 = *(const float4*)&s_src[2 * g][d4 * 4];
            float4 s1 = *(const float4*)&s_src[2 * g + 1][d4 * 4];
            a0 = fmaf(bv.x, s0.x, a0);
            a0 = fmaf(bv.y, s0.y, a0);
            a0 = fmaf(bv.z, s0.z, a0);
            a0 = fmaf(bv.w, s0.w, a0);
            a1 = fmaf(bv.x, s1.x, a1);
            a1 = fmaf(bv.y, s1.y, a1);
            a1 = fmaf(bv.z, s1.z, a1);
            a1 = fmaf(bv.w, s1.w, a1);
        }
        // store [r=ff][hs=h*9+s]
        Wq[(size_t)(r0 + 2 * g) * WQROW + ff * NHS + h * NS + s] = a0;
        Wq[(size_t)(r0 + 2 * g + 1) * WQROW + ff * NHS + h * NS + s] = a1;
    }
}

// ---------------------------------------------------------------------------
// K2a: logits + softmax for 4 heads of one row.
// grid (512 rows, 2 head-groups), 256 threads (t = key index m).
// Wq slice [64 r][36 hs] staged in LDS; 12-r gaussian window contraction
// with 36 accumulators; per-wave softmax (wave = head); weights -> wbuf.
// 1024 blocks = 4/CU = 16 waves/CU (2x round-5 occupancy).
// ---------------------------------------------------------------------------
__global__ __launch_bounds__(256, 4) void k2a_logits(const float* __restrict__ src,
                                                     const float* __restrict__ rel_diss,
                                                     const float* __restrict__ rel_dirs,
                                                     const float* __restrict__ Wq,
                                                     float* __restrict__ wbuf) {
    int row = blockIdx.x;      // b*256 + l
    int b = row >> 8;
    int hg = blockIdx.y;       // head group: heads hg*4 .. hg*4+3
    int m = threadIdx.x;
    __shared__ float s_wq[64 * 36];   // 9 KB: [r][36]
    __shared__ float s_l[4][NL];      // 4 KB: logits

    // --- stage Wq slice (coalesced-ish: 144B runs), LDS writes linear ---
    const float* wrow = Wq + (size_t)row * WQROW + hg * 36;
    #pragma unroll
    for (int i = 0; i < 9; ++i) {
        int flat = i * 256 + m;           // 0..2303 = r*36 + c
        int r = flat / 36, c = flat - 36 * r;
        s_wq[flat] = wrow[r * NHS + c];
    }

    // --- rbf window + spherical harmonics (env folded into sph) ---
    float dist = rel_diss[(size_t)row * NL + m];
    const float* dirp = rel_dirs + ((size_t)row * NL + m) * 3;
    float x = dirp[0], y = dirp[1], z = dirp[2];
    float tcl = fminf(fmaxf(dist * 0.1f, 0.f), 1.f);
    float env = 0.5f * (__cosf(3.14159265358979f * tcl) + 1.f);
    int rc = (int)floorf(dist * 6.3f + 0.5f);          // nearest center
    int rlo = min(max(rc - 6, 0), NR - RWIN);          // window [rlo, rlo+12)
    float sph[NS];
    sph[0] = 0.28209479177387814f * env;
    sph[1] = 0.4886025119029199f * y * env;
    sph[2] = 0.4886025119029199f * z * env;
    sph[3] = 0.4886025119029199f * x * env;
    sph[4] = 1.0925484305920792f * x * y * env;
    sph[5] = 1.0925484305920792f * y * z * env;
    sph[6] = 0.31539156525252005f * (3.f * z * z - 1.f) * env;
    sph[7] = 1.0925484305920792f * x * z * env;
    sph[8] = 0.5462742152960396f * (x * x - y * y) * env;

    __syncthreads();

    // --- rp contraction over the 12-r window, 36 accumulators ---
    float acc[36];
    #pragma unroll
    for (int i = 0; i < 36; ++i) acc[i] = 0.f;
    #pragma unroll 4
    for (int rw = 0; rw < RWIN; ++rw) {
        int r = rlo + rw;
        float df = dist - r * (10.f / 63.f);
        float rbf = __expf(-df * df * 20.48f);   // 1/(2*width^2)
        const float* wp = &s_wq[r * 36];
        #pragma unroll
        for (int q = 0; q < 9; ++q) {
            float4 w = *(const float4*)(wp + q * 4);
            acc[q * 4 + 0] = fmaf(w.x, rbf, acc[q * 4 + 0]);
            acc[q * 4 + 1] = fmaf(w.y, rbf, acc[q * 4 + 1]);
            acc[q * 4 + 2] = fmaf(w.z, rbf, acc[q * 4 + 2]);
            acc[q * 4 + 3] = fmaf(w.w, rbf, acc[q * 4 + 3]);
        }
    }

    // --- per-head: sph-reduce + qk/8 -> logits ---
    const float* qrow = src + (size_t)row * ND;   // wave-uniform -> s_load
    const float4* k4p = (const float4*)(src + ((size_t)b * NL + m) * ND);
    #pragma unroll
    for (int hh = 0; hh < 4; ++hh) {
        int h = hg * 4 + hh;
        float sc = 0.f;
        #pragma unroll
        for (int s = 0; s < NS; ++s) sc = fmaf(sph[s], acc[hh * NS + s], sc);
        float qa0 = 0.f, qa1 = 0.f, qa2 = 0.f, qa3 = 0.f;
        #pragma unroll
        for (int dq = 0; dq < 16; dq += 4) {
            float4 kv0 = k4p[h * 16 + dq + 0];
            float4 kv1 = k4p[h * 16 + dq + 1];
            float4 kv2 = k4p[h * 16 + dq + 2];
            float4 kv3 = k4p[h * 16 + dq + 3];
            qa0 = fmaf(qrow[h * 64 + dq * 4 + 0], kv0.x, qa0);
            qa0 = fmaf(qrow[h * 64 + dq * 4 + 1], kv0.y, qa0);
            qa0 = fmaf(qrow[h * 64 + dq * 4 + 2], kv0.z, qa0);
            qa0 = fmaf(qrow[h * 64 + dq * 4 + 3], kv0.w, qa0);
            qa1 = fmaf(qrow[h * 64 + dq * 4 + 4], kv1.x, qa1);
            qa1 = fmaf(qrow[h * 64 + dq * 4 + 5], kv1.y, qa1);
            qa1 = fmaf(qrow[h * 64 + dq * 4 + 6], kv1.z, qa1);
            qa1 = fmaf(qrow[h * 64 + dq * 4 + 7], kv1.w, qa1);
            qa2 = fmaf(qrow[h * 64 + dq * 4 + 8], kv2.x, qa2);
            qa2 = fmaf(qrow[h * 64 + dq * 4 + 9], kv2.y, qa2);
            qa2 = fmaf(qrow[h * 64 + dq * 4 + 10], kv2.z, qa2);
            qa2 = fmaf(qrow[h * 64 + dq * 4 + 11], kv2.w, qa2);
            qa3 = fmaf(qrow[h * 64 + dq * 4 + 12], kv3.x, qa3);
            qa3 = fmaf(qrow[h * 64 + dq * 4 + 13], kv3.y, qa3);
            qa3 = fmaf(qrow[h * 64 + dq * 4 + 14], kv3.z, qa3);
            qa3 = fmaf(qrow[h * 64 + dq * 4 + 15], kv3.w, qa3);
        }
        s_l[hh][m] = sc + ((qa0 + qa1) + (qa2 + qa3)) * 0.125f;
    }
    __syncthreads();

    // --- softmax: wave wv handles head hg*4+wv; weights -> wbuf[row][h][m] ---
    int wv = m >> 6, lane = m & 63;
    float v0 = s_l[wv][lane], v1 = s_l[wv][lane + 64];
    float v2 = s_l[wv][lane + 128], v3 = s_l[wv][lane + 192];
    float mx = fmaxf(fmaxf(v0, v1), fmaxf(v2, v3));
    #pragma unroll
    for (int off = 32; off; off >>= 1) mx = fmaxf(mx, __shfl_xor(mx, off, 64));
    float p0 = __expf(v0 - mx), p1 = __expf(v1 - mx);
    float p2 = __expf(v2 - mx), p3 = __expf(v3 - mx);
    float sm = p0 + p1 + p2 + p3;
    #pragma unroll
    for (int off = 32; off; off >>= 1) sm += __shfl_xor(sm, off, 64);
    float inv = 1.f / sm;
    float* wout = wbuf + ((size_t)row * NH + hg * 4 + wv) * NL;
    wout[lane] = p0 * inv;
    wout[lane + 64] = p1 * inv;
    wout[lane + 128] = p2 * inv;
    wout[lane + 192] = p3 * inv;
}

// ---------------------------------------------------------------------------
// K2b: V accumulation + residual + LayerNorm1 -> x1buf. grid 512, 256 thr.
// ---------------------------------------------------------------------------
__global__ __launch_bounds__(256) void k2b_pv(const float* __restrict__ src,
                                              const float* __restrict__ wbuf,
                                              const float* __restrict__ gamma1,
                                              const float* __restrict__ beta1,
                                              float* __restrict__ x1buf) {
    int row = blockIdx.x;
    int b = row >> 8;
    int t = threadIdx.x;
    __shared__ float s_w[NH][NL];   // 8 KB
    __shared__ float s_red[8];

    const float* wrow = wbuf + (size_t)row * (NH * NL);
    #pragma unroll
    for (int i = 0; i < 8; ++i) {
        int flat = i * 256 + t;
        ((float*)s_w)[flat] = wrow[flat];
    }
    __syncthreads();

    int d0 = t * 2;            // 0..510
    int h0 = t >> 5;           // head index 0..7
    float a0 = 0.f, a1 = 0.f, b0 = 0.f, b1 = 0.f;
    const float* vbase = src + (size_t)b * NL * ND;
    #pragma unroll 2
    for (int mm = 0; mm < NL; mm += 4) {
        float4 w = *(const float4*)&s_w[h0][mm];
        float2 v0 = *(const float2*)(vbase + (size_t)(mm + 0) * ND + d0);
        float2 v1 = *(const float2*)(vbase + (size_t)(mm + 1) * ND + d0);
        float2 v2 = *(const float2*)(vbase + (size_t)(mm + 2) * ND + d0);
        float2 v3 = *(const float2*)(vbase + (size_t)(mm + 3) * ND + d0);
        a0 = fmaf(w.x, v0.x, a0);
        a1 = fmaf(w.x, v0.y, a1);
        b0 = fmaf(w.y, v1.x, b0);
        b1 = fmaf(w.y, v1.y, b1);
        a0 = fmaf(w.z, v2.x, a0);
        a1 = fmaf(w.z, v2.y, a1);
        b0 = fmaf(w.w, v3.x, b0);
        b1 = fmaf(w.w, v3.y, b1);
    }
    a0 += b0;
    a1 += b1;
    // residual + LayerNorm1 (2 elements per thread)
    const float* qrow = src + (size_t)row * ND;
    float2 s0 = *(const float2*)(qrow + d0);
    float x0 = s0.x + a0, x1v = s0.y + a1;
    float mu = block_sum(x0 + x1v, s_red) * (1.f / 512.f);
    float e0 = x0 - mu, e1 = x1v - mu;
    float var = block_sum(e0 * e0 + e1 * e1, s_red) * (1.f / 512.f);
    float rs = rsqrtf(var + 1e-5f);
    float2 g0 = *(const float2*)(gamma1 + d0), be0 = *(const float2*)(beta1 + d0);
    float* o = x1buf + (size_t)row * ND;
    *(float2*)(o + d0) = make_float2(e0 * rs * g0.x + be0.x, e1 * rs * g0.y + be0.y);
}

// ---------------------------------------------------------------------------
// K3: hbuf = leaky_relu(x1 @ w1 + b1)  [512,512]@[512,2048]
// 32x64 tile, 2x4 microtile, BK=16; grid 32x16 = 512 blocks (2/CU)
// ---------------------------------------------------------------------------
__global__ __launch_bounds__(256) void k3_ffn1(const float* __restrict__ A,
                                               const float* __restrict__ Bw,
                                               const float* __restrict__ bias,
                                               float* __restrict__ C) {
    const int N = 2048, K = 512;
    int n0 = blockIdx.x * 64, m0 = blockIdx.y * 32;
    int t = threadIdx.x;
    int tx = t & 15, ty = t >> 4;          // 16 x 16
    __shared__ float As[16][34];
    __shared__ float Bs[16][64];
    float acc[2][4] = {};
    int am = t >> 3, ak = (t & 7) * 2;     // A loader: 32 rows x 16 k (float2)
    int bk = t >> 4, bn = (t & 15) * 4;    // B loader: 16 rows x 64 n (float4)
    for (int k0 = 0; k0 < K; k0 += 16) {
        float2 av = *(const float2*)(A + (size_t)(m0 + am) * K + k0 + ak);
        float4 bv = *(const float4*)(Bw + (size_t)(k0 + bk) * N + n0 + bn);
        __syncthreads();
        As[ak][am] = av.x;
        As[ak + 1][am] = av.y;
        *(float4*)&Bs[bk][bn] = bv;
        __syncthreads();
        #pragma unroll
        for (int k = 0; k < 16; ++k) {
            float2 a = *(const float2*)&As[k][ty * 2];
            float4 bb = *(const float4*)&Bs[k][tx * 4];
            acc[0][0] = fmaf(a.x, bb.x, acc[0][0]);
            acc[0][1] = fmaf(a.x, bb.y, acc[0][1]);
            acc[0][2] = fmaf(a.x, bb.z, acc[0][2]);
            acc[0][3] = fmaf(a.x, bb.w, acc[0][3]);
            acc[1][0] = fmaf(a.y, bb.x, acc[1][0]);
            acc[1][1] = fmaf(a.y, bb.y, acc[1][1]);
            acc[1][2] = fmaf(a.y, bb.z, acc[1][2]);
            acc[1][3] = fmaf(a.y, bb.w, acc[1][3]);
        }
    }
    #pragma unroll
    for (int i = 0; i < 2; ++i) {
        int rrow = m0 + ty * 2 + i;
        int cc = n0 + tx * 4;
        float v0 = acc[i][0] + bias[cc + 0];
        float v1 = acc[i][1] + bias[cc + 1];
        float v2 = acc[i][2] + bias[cc + 2];
        float v3 = acc[i][3] + bias[cc + 3];
        float4 ov;
        ov.x = v0 >= 0.f ? v0 : 0.01f * v0;
        ov.y = v1 >= 0.f ? v1 : 0.01f * v1;
        ov.z = v2 >= 0.f ? v2 : 0.01f * v2;
        ov.w = v3 >= 0.f ? v3 : 0.01f * v3;
        *(float4*)(C + (size_t)rrow * N + cc) = ov;
    }
}

// ---------------------------------------------------------------------------
// K4: zpart[ks] = hbuf[:, ks*512:(ks+1)*512] @ w2[ks*512:(ks+1)*512, :]
// 32x64 tile, 2x4 microtile, split-K=4; grid 8x16x4 = 512 blocks
// ---------------------------------------------------------------------------
__global__ __launch_bounds__(256) void k4_ffn2(const float* __restrict__ A,
                                               const float* __restrict__ Bw,
                                               float* __restrict__ Cp) {
    const int N = 512, K = 2048;
    int n0 = blockIdx.x * 64, m0 = blockIdx.y * 32;
    int ks = blockIdx.z;
    int t = threadIdx.x;
    int tx = t & 15, ty = t >> 4;
    __shared__ float As[16][34];
    __shared__ float Bs[16][64];
    float acc[2][4] = {};
    int am = t >> 3, ak = (t & 7) * 2;
    int bk = t >> 4, bn = (t & 15) * 4;
    int kbase = ks * 512;
    for (int k0 = kbase; k0 < kbase + 512; k0 += 16) {
        float2 av = *(const float2*)(A + (size_t)(m0 + am) * K + k0 + ak);
        float4 bv = *(const float4*)(Bw + (size_t)(k0 + bk) * N + n0 + bn);
        __syncthreads();
        As[ak][am] = av.x;
        As[ak + 1][am] = av.y;
        *(float4*)&Bs[bk][bn] = bv;
        __syncthreads();
        #pragma unroll
        for (int k = 0; k < 16; ++k) {
            float2 a = *(const float2*)&As[k][ty * 2];
            float4 bb = *(const float4*)&Bs[k][tx * 4];
            acc[0][0] = fmaf(a.x, bb.x, acc[0][0]);
            acc[0][1] = fmaf(a.x, bb.y, acc[0][1]);
            acc[0][2] = fmaf(a.x, bb.z, acc[0][2]);
            acc[0][3] = fmaf(a.x, bb.w, acc[0][3]);
            acc[1][0] = fmaf(a.y, bb.x, acc[1][0]);
            acc[1][1] = fmaf(a.y, bb.y, acc[1][1]);
            acc[1][2] = fmaf(a.y, bb.z, acc[1][2]);
            acc[1][3] = fmaf(a.y, bb.w, acc[1][3]);
        }
    }
    float* out = Cp + ((size_t)ks << 18);
    #pragma unroll
    for (int i = 0; i < 2; ++i) {
        int rrow = m0 + ty * 2 + i;
        int cc = n0 + tx * 4;
        *(float4*)(out + (size_t)rrow * N + cc) =
            make_float4(acc[i][0], acc[i][1], acc[i][2], acc[i][3]);
    }
}

// ---------------------------------------------------------------------------
// K5: z = x1 + b2 + sum_ks zpart[ks]; out = LayerNorm2(z)
// ---------------------------------------------------------------------------
__global__ __launch_bounds__(256) void k5_final(const float* __restrict__ x1buf,
                                                const float* __restrict__ zpart,
                                                const float* __restrict__ b2,
                                                const float* __restrict__ gamma2,
                                                const float* __restrict__ beta2,
                                                float* __restrict__ out) {
    int row = blockIdx.x;
    int t = threadIdx.x;
    int d0 = t * 2;
    __shared__ float s_red[8];
    size_t off = (size_t)row * ND + d0;
    float2 v = *(const float2*)(x1buf + off);
    float2 bb = *(const float2*)(b2 + d0);
    float z0 = v.x + bb.x, z1 = v.y + bb.y;
    #pragma unroll
    for (int ks = 0; ks < 4; ++ks) {
        float2 p = *(const float2*)(zpart + ((size_t)ks << 18) + off);
        z0 += p.x;
        z1 += p.y;
    }
    float mu = block_sum(z0 + z1, s_red) * (1.f / 512.f);
    float e0 = z0 - mu, e1 = z1 - mu;
    float var = block_sum(e0 * e0 + e1 * e1, s_red) * (1.f / 512.f);
    float rs = rsqrtf(var + 1e-5f);
    float2 g = *(const float2*)(gamma2 + d0), be = *(const float2*)(beta2 + d0);
    *(float2*)(out + off) = make_float2(e0 * rs * g.x + be.x, e1 * rs * g.y + be.y);
}

// ---------------------------------------------------------------------------
extern "C" void kernel_launch(void* const* d_in, const int* in_sizes, int n_in,
                              void* d_out, int out_size, void* d_ws, size_t ws_size,
                              hipStream_t stream) {
    const float* src      = (const float*)d_in[0];
    const float* rel_diss = (const float*)d_in[1];
    const float* rel_dirs = (const float*)d_in[2];
    const float* rp_w     = (const float*)d_in[3];
    // d_in[4] = rp_b: constant over softmax axis -> cancels exactly; skipped
    const float* w1  = (const float*)d_in[5];
    const float* b1  = (const float*)d_in[6];
    const float* w2  = (const float*)d_in[7];
    const float* b2  = (const float*)d_in[8];
    const float* g1  = (const float*)d_in[9];
    const float* be1 = (const float*)d_in[10];
    const float* g2  = (const float*)d_in[11];
    const float* be2 = (const float*)d_in[12];
    float* out = (float*)d_out;

    float* ws = (float*)d_ws;
    float* x1buf = ws;                       // 512*512        = 262144
    float* hbuf  = x1buf + 262144;           // 512*2048       = 1048576
    float* zpart = hbuf + 1048576;           // 4*512*512      = 1048576
    float* Wq    = zpart + 1048576;          // 512*4608       = 2359296
    // total 4,718,592 floats = 18 MiB of d_ws
    // wbuf (attention weights, 512*8*256 = 1048576 floats) ALIASES hbuf:
    // written by k2a, read by k2b, then dead before k3 writes hbuf.
    float* wbuf = hbuf;

    k1_wq<<<dim3(64, 8), 256, 0, stream>>>(src, rp_w, Wq);
    k2a_logits<<<dim3(512, 2), 256, 0, stream>>>(src, rel_diss, rel_dirs, Wq, wbuf);
    k2b_pv<<<dim3(512), 256, 0, stream>>>(src, wbuf, g1, be1, x1buf);
    k3_ffn1<<<dim3(32, 16), 256, 0, stream>>>(x1buf, w1, b1, hbuf);
    k4_ffn2<<<dim3(8, 16, 4), 256, 0, stream>>>(hbuf, w2, zpart);
    k5_final<<<dim3(512), 256, 0, stream>>>(x1buf, zpart, b2, g2, be2, out);
}

// Round 7
// 114.516 us; speedup vs baseline: 1.2655x; 1.2655x over previous
//
#include <hip/hip_runtime.h>

// Problem constants
// B=2, L=256, D=512, H=8, Dh=64, NUM_RADIAL=64, N_SPH=9, F=576
#define NB 2
#define NL 256
#define ND 512
#define NH 8
#define NDH 64
#define NR 64
#define NS 9
#define NF 576
#define NHS 72      // NH*NS
#define WQROW 4608  // NR*NHS
#define RWIN 12     // rbf window: terms beyond 5.5*delta < 2e-7 -> negligible

__device__ __forceinline__ float block_sum(float v, float* s_red) {
    #pragma unroll
    for (int off = 32; off; off >>= 1) v += __shfl_xor(v, off, 64);
    __syncthreads();  // protect s_red from previous use
    if ((threadIdx.x & 63) == 0) s_red[threadIdx.x >> 6] = v;
    __syncthreads();
    return s_red[0] + s_red[1] + s_red[2] + s_red[3];
}

// ---------------------------------------------------------------------------
// K1: Wq[row][r*72 + h*9+s] = sum_d rp_w[(s*64+r)][h*64+d] * src[row][h*64+d]
// grid (64 rowtiles of 8, 8 heads), 256 threads.
// ---------------------------------------------------------------------------
__global__ __launch_bounds__(256) void k1_wq(const float* __restrict__ src,
                                             const float* __restrict__ rp_w,
                                             float* __restrict__ Wq) {
    int rt = blockIdx.x;   // 64 rowtiles x 8 rows
    int h  = blockIdx.y;
    int t  = threadIdx.x;
    __shared__ float s_src[8][64];   // 2 KB
    __shared__ float s_B[64 * 64];   // 16 KB, slot-swizzled rows
    int r0 = rt * 8;
    {   // stage src tile: 8 rows x 64 d, float2 per thread, coalesced
        int sr = t >> 5;
        int sc = (t & 31) * 2;
        *(float2*)&s_src[sr][sc] =
            *(const float2*)(src + (size_t)(r0 + sr) * ND + h * 64 + sc);
    }
    int ff = t & 63;        // = r index of output
    int g  = t >> 6;        // wave id 0..3 -> rows 2g, 2g+1
    int lr = t >> 2;        // loader row 0..63
    int lq = t & 3;         // loader quarter
    const float* bsrc = rp_w + h * 64;

    #pragma unroll 1
    for (int s = 0; s < NS; ++s) {
        __syncthreads();   // protect s_B (and s_src on first iter)
        #pragma unroll
        for (int i = 0; i < 4; ++i) {
            int slot = i * 4 + lq;                 // 0..15, lanes consecutive
            float4 v = *(const float4*)(bsrc + (size_t)(s * 64 + lr) * ND + slot * 4);
            int sw = slot ^ (lr & 7);
            *(float4*)&s_B[lr * 64 + sw * 4] = v;
        }
        __syncthreads();
        float a0 = 0.f, a1 = 0.f;
        #pragma unroll
        for (int d4 = 0; d4 < 16; ++d4) {
            int sw = d4 ^ (ff & 7);
            float4 bv = *(const float4*)&s_B[ff * 64 + sw * 4];
            float4 s0 = *(const float4*)&s_src[2 * g][d4 * 4];
            float4 s1 = *(const float4*)&s_src[2 * g + 1][d4 * 4];
            a0 = fmaf(bv.x, s0.x, a0);
            a0 = fmaf(bv.y, s0.y, a0);
            a0 = fmaf(bv.z, s0.z, a0);
            a0 = fmaf(bv.w, s0.w, a0);
            a1 = fmaf(bv.x, s1.x, a1);
            a1 = fmaf(bv.y, s1.y, a1);
            a1 = fmaf(bv.z, s1.z, a1);
            a1 = fmaf(bv.w, s1.w, a1);
        }
        // store [r=ff][hs=h*9+s]
        Wq[(size_t)(r0 + 2 * g) * WQROW + ff * NHS + h * NS + s] = a0;
        Wq[(size_t)(r0 + 2 * g + 1) * WQROW + ff * NHS + h * NS + s] = a1;
    }
}

// ---------------------------------------------------------------------------
// K_QK: sbuf[b,h,l,m] = 0.125 * sum_d src[b,l,h64+d]*src[b,m,h64+d]
// Tiled GEMM, 32(l) x 64(m) tile; B (=K rows) transposed through LDS so all
// global loads are coalesced. grid (4 mtiles, 8 ltiles, 16 bh).
// ---------------------------------------------------------------------------
__global__ __launch_bounds__(256) void k_qk(const float* __restrict__ src,
                                            float* __restrict__ sbuf) {
    int mt = blockIdx.x, lt = blockIdx.y, bh = blockIdx.z;
    int b = bh >> 3, h = bh & 7;
    int m0 = mt * 64, l0 = lt * 32;
    int t = threadIdx.x;
    __shared__ float s_A[32][68];   // [l][d], padded
    __shared__ float s_B[64][68];   // [d][m], padded (transposed K)

    // stage A: 32 rows x 64 d, 2 float4/thread, coalesced
    #pragma unroll
    for (int i = 0; i < 2; ++i) {
        int idx = i * 256 + t;
        int row = idx >> 4, c4 = idx & 15;
        float4 v = *(const float4*)(src + (size_t)(b * NL + l0 + row) * ND + h * 64 + c4 * 4);
        *(float4*)&s_A[row][c4 * 4] = v;
    }
    // stage B transposed: thread -> K row mr=t>>2, d-quarter qd=t&3
    {
        int mr = t >> 2, qd = t & 3;
        const float* kp = src + (size_t)(b * NL + m0 + mr) * ND + h * 64 + qd * 16;
        #pragma unroll
        for (int q = 0; q < 4; ++q) {
            float4 v = *(const float4*)(kp + q * 4);
            int d = qd * 16 + q * 4;
            s_B[d + 0][mr] = v.x;
            s_B[d + 1][mr] = v.y;
            s_B[d + 2][mr] = v.z;
            s_B[d + 3][mr] = v.w;
        }
    }
    __syncthreads();

    int tx = t & 15, ty = t >> 4;
    int ty2 = ty * 2;
    float acc[2][4] = {};
    #pragma unroll
    for (int d = 0; d < 64; ++d) {
        float a0 = s_A[ty2][d];
        float a1 = s_A[ty2 + 1][d];
        float4 bv = *(const float4*)&s_B[d][tx * 4];
        acc[0][0] = fmaf(a0, bv.x, acc[0][0]);
        acc[0][1] = fmaf(a0, bv.y, acc[0][1]);
        acc[0][2] = fmaf(a0, bv.z, acc[0][2]);
        acc[0][3] = fmaf(a0, bv.w, acc[0][3]);
        acc[1][0] = fmaf(a1, bv.x, acc[1][0]);
        acc[1][1] = fmaf(a1, bv.y, acc[1][1]);
        acc[1][2] = fmaf(a1, bv.z, acc[1][2]);
        acc[1][3] = fmaf(a1, bv.w, acc[1][3]);
    }
    #pragma unroll
    for (int i = 0; i < 2; ++i) {
        size_t off = ((size_t)bh * NL + l0 + ty2 + i) * NL + m0 + tx * 4;
        *(float4*)(sbuf + off) = make_float4(acc[i][0] * 0.125f, acc[i][1] * 0.125f,
                                             acc[i][2] * 0.125f, acc[i][3] * 0.125f);
    }
}

// ---------------------------------------------------------------------------
// K2a: logits + softmax for 4 heads of one row.
// grid (512 rows, 2 head-groups), 256 threads (t = key index m).
// Wq slice [64 r][36 hs] staged in LDS; 12-r gaussian window contraction;
// base QK read COALESCED from sbuf. weights -> wbuf.
// ---------------------------------------------------------------------------
__global__ __launch_bounds__(256, 4) void k2a_logits(const float* __restrict__ rel_diss,
                                                     const float* __restrict__ rel_dirs,
                                                     const float* __restrict__ Wq,
                                                     const float* __restrict__ sbuf,
                                                     float* __restrict__ wbuf) {
    int row = blockIdx.x;      // b*256 + l
    int b = row >> 8;
    int l = row & 255;
    int hg = blockIdx.y;       // head group: heads hg*4 .. hg*4+3
    int m = threadIdx.x;
    __shared__ float s_wq[64 * 36];   // 9 KB: [r][36]
    __shared__ float s_l[4][NL];      // 4 KB: logits

    // --- stage Wq slice (144B runs), LDS writes linear ---
    const float* wrow = Wq + (size_t)row * WQROW + hg * 36;
    #pragma unroll
    for (int i = 0; i < 9; ++i) {
        int flat = i * 256 + m;           // 0..2303 = r*36 + c
        int r = flat / 36, c = flat - 36 * r;
        s_wq[flat] = wrow[r * NHS + c];
    }

    // --- rbf window + spherical harmonics (env folded into sph) ---
    float dist = rel_diss[(size_t)row * NL + m];
    const float* dirp = rel_dirs + ((size_t)row * NL + m) * 3;
    float x = dirp[0], y = dirp[1], z = dirp[2];
    float tcl = fminf(fmaxf(dist * 0.1f, 0.f), 1.f);
    float env = 0.5f * (__cosf(3.14159265358979f * tcl) + 1.f);
    int rc = (int)floorf(dist * 6.3f + 0.5f);          // nearest center
    int rlo = min(max(rc - 6, 0), NR - RWIN);          // window [rlo, rlo+12)
    float sph[NS];
    sph[0] = 0.28209479177387814f * env;
    sph[1] = 0.4886025119029199f * y * env;
    sph[2] = 0.4886025119029199f * z * env;
    sph[3] = 0.4886025119029199f * x * env;
    sph[4] = 1.0925484305920792f * x * y * env;
    sph[5] = 1.0925484305920792f * y * z * env;
    sph[6] = 0.31539156525252005f * (3.f * z * z - 1.f) * env;
    sph[7] = 1.0925484305920792f * x * z * env;
    sph[8] = 0.5462742152960396f * (x * x - y * y) * env;

    __syncthreads();

    // --- rp contraction over the 12-r window, 36 accumulators ---
    float acc[36];
    #pragma unroll
    for (int i = 0; i < 36; ++i) acc[i] = 0.f;
    #pragma unroll 4
    for (int rw = 0; rw < RWIN; ++rw) {
        int r = rlo + rw;
        float df = dist - r * (10.f / 63.f);
        float rbf = __expf(-df * df * 20.48f);   // 1/(2*width^2)
        const float* wp = &s_wq[r * 36];
        #pragma unroll
        for (int q = 0; q < 9; ++q) {
            float4 w = *(const float4*)(wp + q * 4);
            acc[q * 4 + 0] = fmaf(w.x, rbf, acc[q * 4 + 0]);
            acc[q * 4 + 1] = fmaf(w.y, rbf, acc[q * 4 + 1]);
            acc[q * 4 + 2] = fmaf(w.z, rbf, acc[q * 4 + 2]);
            acc[q * 4 + 3] = fmaf(w.w, rbf, acc[q * 4 + 3]);
        }
    }

    // --- per-head: sph-reduce + coalesced base read -> logits ---
    const float* sb = sbuf + (((size_t)(b * NH + hg * 4) * NL) + l) * NL + m;
    #pragma unroll
    for (int hh = 0; hh < 4; ++hh) {
        float sc = 0.f;
        #pragma unroll
        for (int s = 0; s < NS; ++s) sc = fmaf(sph[s], acc[hh * NS + s], sc);
        s_l[hh][m] = sc + sb[(size_t)hh * NL * NL];
    }
    __syncthreads();

    // --- softmax: wave wv handles head hg*4+wv; weights -> wbuf[row][h][m] ---
    int wv = m >> 6, lane = m & 63;
    float v0 = s_l[wv][lane], v1 = s_l[wv][lane + 64];
    float v2 = s_l[wv][lane + 128], v3 = s_l[wv][lane + 192];
    float mx = fmaxf(fmaxf(v0, v1), fmaxf(v2, v3));
    #pragma unroll
    for (int off = 32; off; off >>= 1) mx = fmaxf(mx, __shfl_xor(mx, off, 64));
    float p0 = __expf(v0 - mx), p1 = __expf(v1 - mx);
    float p2 = __expf(v2 - mx), p3 = __expf(v3 - mx);
    float sm = p0 + p1 + p2 + p3;
    #pragma unroll
    for (int off = 32; off; off >>= 1) sm += __shfl_xor(sm, off, 64);
    float inv = 1.f / sm;
    float* wout = wbuf + ((size_t)row * NH + hg * 4 + wv) * NL;
    wout[lane] = p0 * inv;
    wout[lane + 64] = p1 * inv;
    wout[lane + 128] = p2 * inv;
    wout[lane + 192] = p3 * inv;
}

// ---------------------------------------------------------------------------
// K2b: V accumulation + residual + LayerNorm1 -> x1buf. grid 512, 256 thr.
// ---------------------------------------------------------------------------
__global__ __launch_bounds__(256) void k2b_pv(const float* __restrict__ src,
                                              const float* __restrict__ wbuf,
                                              const float* __restrict__ gamma1,
                                              const float* __restrict__ beta1,
                                              float* __restrict__ x1buf) {
    int row = blockIdx.x;
    int b = row >> 8;
    int t = threadIdx.x;
    __shared__ float s_w[NH][NL];   // 8 KB
    __shared__ float s_red[8];

    const float* wrow = wbuf + (size_t)row * (NH * NL);
    #pragma unroll
    for (int i = 0; i < 8; ++i) {
        int flat = i * 256 + t;
        ((float*)s_w)[flat] = wrow[flat];
    }
    __syncthreads();

    int d0 = t * 2;            // 0..510
    int h0 = t >> 5;           // head index 0..7
    float a0 = 0.f, a1 = 0.f, b0 = 0.f, b1 = 0.f;
    const float* vbase = src + (size_t)b * NL * ND;
    #pragma unroll 2
    for (int mm = 0; mm < NL; mm += 4) {
        float4 w = *(const float4*)&s_w[h0][mm];
        float2 v0 = *(const float2*)(vbase + (size_t)(mm + 0) * ND + d0);
        float2 v1 = *(const float2*)(vbase + (size_t)(mm + 1) * ND + d0);
        float2 v2 = *(const float2*)(vbase + (size_t)(mm + 2) * ND + d0);
        float2 v3 = *(const float2*)(vbase + (size_t)(mm + 3) * ND + d0);
        a0 = fmaf(w.x, v0.x, a0);
        a1 = fmaf(w.x, v0.y, a1);
        b0 = fmaf(w.y, v1.x, b0);
        b1 = fmaf(w.y, v1.y, b1);
        a0 = fmaf(w.z, v2.x, a0);
        a1 = fmaf(w.z, v2.y, a1);
        b0 = fmaf(w.w, v3.x, b0);
        b1 = fmaf(w.w, v3.y, b1);
    }
    a0 += b0;
    a1 += b1;
    // residual + LayerNorm1 (2 elements per thread)
    const float* qrow = src + (size_t)row * ND;
    float2 s0 = *(const float2*)(qrow + d0);
    float x0 = s0.x + a0, x1v = s0.y + a1;
    float mu = block_sum(x0 + x1v, s_red) * (1.f / 512.f);
    float e0 = x0 - mu, e1 = x1v - mu;
    float var = block_sum(e0 * e0 + e1 * e1, s_red) * (1.f / 512.f);
    float rs = rsqrtf(var + 1e-5f);
    float2 g0 = *(const float2*)(gamma1 + d0), be0 = *(const float2*)(beta1 + d0);
    float* o = x1buf + (size_t)row * ND;
    *(float2*)(o + d0) = make_float2(e0 * rs * g0.x + be0.x, e1 * rs * g0.y + be0.y);
}

// ---------------------------------------------------------------------------
// K3: hbuf = leaky_relu(x1 @ w1 + b1)  [512,512]@[512,2048]
// 32x64 tile, 2x4 microtile, BK=16; grid 32x16 = 512 blocks (2/CU)
// ---------------------------------------------------------------------------
__global__ __launch_bounds__(256) void k3_ffn1(const float* __restrict__ A,
                                               const float* __restrict__ Bw,
                                               const float* __restrict__ bias,
                                               float* __restrict__ C) {
    const int N = 2048, K = 512;
    int n0 = blockIdx.x * 64, m0 = blockIdx.y * 32;
    int t = threadIdx.x;
    int tx = t & 15, ty = t >> 4;          // 16 x 16
    __shared__ float As[16][34];
    __shared__ float Bs[16][64];
    float acc[2][4] = {};
    int am = t >> 3, ak = (t & 7) * 2;     // A loader: 32 rows x 16 k (float2)
    int bk = t >> 4, bn = (t & 15) * 4;    // B loader: 16 rows x 64 n (float4)
    for (int k0 = 0; k0 < K; k0 += 16) {
        float2 av = *(const float2*)(A + (size_t)(m0 + am) * K + k0 + ak);
        float4 bv = *(const float4*)(Bw + (size_t)(k0 + bk) * N + n0 + bn);
        __syncthreads();
        As[ak][am] = av.x;
        As[ak + 1][am] = av.y;
        *(float4*)&Bs[bk][bn] = bv;
        __syncthreads();
        #pragma unroll
        for (int k = 0; k < 16; ++k) {
            float2 a = *(const float2*)&As[k][ty * 2];
            float4 bb = *(const float4*)&Bs[k][tx * 4];
            acc[0][0] = fmaf(a.x, bb.x, acc[0][0]);
            acc[0][1] = fmaf(a.x, bb.y, acc[0][1]);
            acc[0][2] = fmaf(a.x, bb.z, acc[0][2]);
            acc[0][3] = fmaf(a.x, bb.w, acc[0][3]);
            acc[1][0] = fmaf(a.y, bb.x, acc[1][0]);
            acc[1][1] = fmaf(a.y, bb.y, acc[1][1]);
            acc[1][2] = fmaf(a.y, bb.z, acc[1][2]);
            acc[1][3] = fmaf(a.y, bb.w, acc[1][3]);
        }
    }
    #pragma unroll
    for (int i = 0; i < 2; ++i) {
        int rrow = m0 + ty * 2 + i;
        int cc = n0 + tx * 4;
        float v0 = acc[i][0] + bias[cc + 0];
        float v1 = acc[i][1] + bias[cc + 1];
        float v2 = acc[i][2] + bias[cc + 2];
        float v3 = acc[i][3] + bias[cc + 3];
        float4 ov;
        ov.x = v0 >= 0.f ? v0 : 0.01f * v0;
        ov.y = v1 >= 0.f ? v1 : 0.01f * v1;
        ov.z = v2 >= 0.f ? v2 : 0.01f * v2;
        ov.w = v3 >= 0.f ? v3 : 0.01f * v3;
        *(float4*)(C + (size_t)rrow * N + cc) = ov;
    }
}

// ---------------------------------------------------------------------------
// K4: zpart[ks] = hbuf[:, ks*512:(ks+1)*512] @ w2[ks*512:(ks+1)*512, :]
// 32x64 tile, 2x4 microtile, split-K=4; grid 8x16x4 = 512 blocks
// ---------------------------------------------------------------------------
__global__ __launch_bounds__(256) void k4_ffn2(const float* __restrict__ A,
                                               const float* __restrict__ Bw,
                                               float* __restrict__ Cp) {
    const int N = 512, K = 2048;
    int n0 = blockIdx.x * 64, m0 = blockIdx.y * 32;
    int ks = blockIdx.z;
    int t = threadIdx.x;
    int tx = t & 15, ty = t >> 4;
    __shared__ float As[16][34];
    __shared__ float Bs[16][64];
    float acc[2][4] = {};
    int am = t >> 3, ak = (t & 7) * 2;
    int bk = t >> 4, bn = (t & 15) * 4;
    int kbase = ks * 512;
    for (int k0 = kbase; k0 < kbase + 512; k0 += 16) {
        float2 av = *(const float2*)(A + (size_t)(m0 + am) * K + k0 + ak);
        float4 bv = *(const float4*)(Bw + (size_t)(k0 + bk) * N + n0 + bn);
        __syncthreads();
        As[ak][am] = av.x;
        As[ak + 1][am] = av.y;
        *(float4*)&Bs[bk][bn] = bv;
        __syncthreads();
        #pragma unroll
        for (int k = 0; k < 16; ++k) {
            float2 a = *(const float2*)&As[k][ty * 2];
            float4 bb = *(const float4*)&Bs[k][tx * 4];
            acc[0][0] = fmaf(a.x, bb.x, acc[0][0]);
            acc[0][1] = fmaf(a.x, bb.y, acc[0][1]);
            acc[0][2] = fmaf(a.x, bb.z, acc[0][2]);
            acc[0][3] = fmaf(a.x, bb.w, acc[0][3]);
            acc[1][0] = fmaf(a.y, bb.x, acc[1][0]);
            acc[1][1] = fmaf(a.y, bb.y, acc[1][1]);
            acc[1][2] = fmaf(a.y, bb.z, acc[1][2]);
            acc[1][3] = fmaf(a.y, bb.w, acc[1][3]);
        }
    }
    float* out = Cp + ((size_t)ks << 18);
    #pragma unroll
    for (int i = 0; i < 2; ++i) {
        int rrow = m0 + ty * 2 + i;
        int cc = n0 + tx * 4;
        *(float4*)(out + (size_t)rrow * N + cc) =
            make_float4(acc[i][0], acc[i][1], acc[i][2], acc[i][3]);
    }
}

// ---------------------------------------------------------------------------
// K5: z = x1 + b2 + sum_ks zpart[ks]; out = LayerNorm2(z)
// ---------------------------------------------------------------------------
__global__ __launch_bounds__(256) void k5_final(const float* __restrict__ x1buf,
                                                const float* __restrict__ zpart,
                                                const float* __restrict__ b2,
                                                const float* __restrict__ gamma2,
                                                const float* __restrict__ beta2,
                                                float* __restrict__ out) {
    int row = blockIdx.x;
    int t = threadIdx.x;
    int d0 = t * 2;
    __shared__ float s_red[8];
    size_t off = (size_t)row * ND + d0;
    float2 v = *(const float2*)(x1buf + off);
    float2 bb = *(const float2*)(b2 + d0);
    float z0 = v.x + bb.x, z1 = v.y + bb.y;
    #pragma unroll
    for (int ks = 0; ks < 4; ++ks) {
        float2 p = *(const float2*)(zpart + ((size_t)ks << 18) + off);
        z0 += p.x;
        z1 += p.y;
    }
    float mu = block_sum(z0 + z1, s_red) * (1.f / 512.f);
    float e0 = z0 - mu, e1 = z1 - mu;
    float var = block_sum(e0 * e0 + e1 * e1, s_red) * (1.f / 512.f);
    float rs = rsqrtf(var + 1e-5f);
    float2 g = *(const float2*)(gamma2 + d0), be = *(const float2*)(beta2 + d0);
    *(float2*)(out + off) = make_float2(e0 * rs * g.x + be.x, e1 * rs * g.y + be.y);
}

// ---------------------------------------------------------------------------
extern "C" void kernel_launch(void* const* d_in, const int* in_sizes, int n_in,
                              void* d_out, int out_size, void* d_ws, size_t ws_size,
                              hipStream_t stream) {
    const float* src      = (const float*)d_in[0];
    const float* rel_diss = (const float*)d_in[1];
    const float* rel_dirs = (const float*)d_in[2];
    const float* rp_w     = (const float*)d_in[3];
    // d_in[4] = rp_b: constant over softmax axis -> cancels exactly; skipped
    const float* w1  = (const float*)d_in[5];
    const float* b1  = (const float*)d_in[6];
    const float* w2  = (const float*)d_in[7];
    const float* b2  = (const float*)d_in[8];
    const float* g1  = (const float*)d_in[9];
    const float* be1 = (const float*)d_in[10];
    const float* g2  = (const float*)d_in[11];
    const float* be2 = (const float*)d_in[12];
    float* out = (float*)d_out;

    float* ws = (float*)d_ws;
    float* x1buf = ws;                       // 512*512        = 262144
    float* hbuf  = x1buf + 262144;           // 512*2048       = 1048576
    float* zpart = hbuf + 1048576;           // 4*512*512      = 1048576
    float* Wq    = zpart + 1048576;          // 512*4608       = 2359296
    // total 4,718,592 floats = 18 MiB of d_ws
    // ALIASES (lifetimes disjoint):
    //   wbuf (attn weights, 512*8*256 = 1M floats) = hbuf: k2a writes, k2b
    //     reads, dead before k3 writes hbuf.
    //   sbuf (base QK logits, 16*256*256 = 1M floats) = zpart: k_qk writes,
    //     k2a reads, dead before k4 writes zpart.
    float* wbuf = hbuf;
    float* sbuf = zpart;

    k1_wq<<<dim3(64, 8), 256, 0, stream>>>(src, rp_w, Wq);
    k_qk<<<dim3(4, 8, 16), 256, 0, stream>>>(src, sbuf);
    k2a_logits<<<dim3(512, 2), 256, 0, stream>>>(rel_diss, rel_dirs, Wq, sbuf, wbuf);
    k2b_pv<<<dim3(512), 256, 0, stream>>>(src, wbuf, g1, be1, x1buf);
    k3_ffn1<<<dim3(32, 16), 256, 0, stream>>>(x1buf, w1, b1, hbuf);
    k4_ffn2<<<dim3(8, 16, 4), 256, 0, stream>>>(hbuf, w2, zpart);
    k5_final<<<dim3(512), 256, 0, stream>>>(x1buf, zpart, b2, g2, be2, out);
}

// Round 8
// 84.618 us; speedup vs baseline: 1.7126x; 1.3533x over previous
//
#include <hip/hip_runtime.h>

// Problem constants
// B=2, L=256, D=512, H=8, Dh=64, NUM_RADIAL=64, N_SPH=9, F=576
#define NB 2
#define NL 256
#define ND 512
#define NH 8
#define NDH 64
#define NR 64
#define NS 9
#define NF 576
#define NHS 72      // NH*NS
#define WQROW 4608  // NR*NHS
#define RWIN 12     // rbf window: terms beyond 5.5*delta < 2e-7 -> negligible

typedef __attribute__((ext_vector_type(8))) short bf16x8;
typedef __attribute__((ext_vector_type(4))) float f32x4;

__device__ __forceinline__ ushort f2b(float f) {   // fp32 -> bf16 RNE
    union { float f; unsigned u; } c; c.f = f;
    unsigned u = c.u;
    return (ushort)((u + 0x7FFF + ((u >> 16) & 1)) >> 16);
}

__device__ __forceinline__ float block_sum(float v, float* s_red) {
    #pragma unroll
    for (int off = 32; off; off >>= 1) v += __shfl_xor(v, off, 64);
    __syncthreads();  // protect s_red from previous use
    if ((threadIdx.x & 63) == 0) s_red[threadIdx.x >> 6] = v;
    __syncthreads();
    return s_red[0] + s_red[1] + s_red[2] + s_red[3];
}

// ---------------------------------------------------------------------------
// K_T2B: out[n][k] = bf16(in[k][n]); in [K][N] fp32. grid (N/64, K/64).
// ---------------------------------------------------------------------------
__global__ __launch_bounds__(256) void k_t2b(const float* __restrict__ in,
                                             ushort* __restrict__ out,
                                             int K, int N) {
    int n0 = blockIdx.x * 64, k0 = blockIdx.y * 64;
    int t = threadIdx.x;
    __shared__ float tile[64][65];
    int r = t >> 4, c4 = (t & 15) * 4;
    #pragma unroll
    for (int i = 0; i < 4; ++i) {
        int kk = i * 16 + r;
        float4 v = *(const float4*)(in + (size_t)(k0 + kk) * N + n0 + c4);
        tile[kk][c4 + 0] = v.x;
        tile[kk][c4 + 1] = v.y;
        tile[kk][c4 + 2] = v.z;
        tile[kk][c4 + 3] = v.w;
    }
    __syncthreads();
    int rr = t >> 2, cq = (t & 3) * 16;
    ushort buf[16];
    #pragma unroll
    for (int j = 0; j < 16; ++j) buf[j] = f2b(tile[cq + j][rr]);
    ushort* op = out + (size_t)(n0 + rr) * K + k0 + cq;
    *(uint4*)(op) = *(uint4*)&buf[0];
    *(uint4*)(op + 8) = *(uint4*)&buf[8];
}

// ---------------------------------------------------------------------------
// K1: Wq[row][r*72 + h*9+s] = sum_d rp_w[(s*64+r)][h*64+d] * src[row][h*64+d]
// ---------------------------------------------------------------------------
__global__ __launch_bounds__(256) void k1_wq(const float* __restrict__ src,
                                             const float* __restrict__ rp_w,
                                             float* __restrict__ Wq) {
    int rt = blockIdx.x;   // 64 rowtiles x 8 rows
    int h  = blockIdx.y;
    int t  = threadIdx.x;
    __shared__ float s_src[8][64];   // 2 KB
    __shared__ float s_B[64 * 64];   // 16 KB, slot-swizzled rows
    int r0 = rt * 8;
    {
        int sr = t >> 5;
        int sc = (t & 31) * 2;
        *(float2*)&s_src[sr][sc] =
            *(const float2*)(src + (size_t)(r0 + sr) * ND + h * 64 + sc);
    }
    int ff = t & 63;
    int g  = t >> 6;
    int lr = t >> 2;
    int lq = t & 3;
    const float* bsrc = rp_w + h * 64;

    #pragma unroll 1
    for (int s = 0; s < NS; ++s) {
        __syncthreads();
        #pragma unroll
        for (int i = 0; i < 4; ++i) {
            int slot = i * 4 + lq;
            float4 v = *(const float4*)(bsrc + (size_t)(s * 64 + lr) * ND + slot * 4);
            int sw = slot ^ (lr & 7);
            *(float4*)&s_B[lr * 64 + sw * 4] = v;
        }
        __syncthreads();
        float a0 = 0.f, a1 = 0.f;
        #pragma unroll
        for (int d4 = 0; d4 < 16; ++d4) {
            int sw = d4 ^ (ff & 7);
            float4 bv = *(const float4*)&s_B[ff * 64 + sw * 4];
            float4 s0 = *(const float4*)&s_src[2 * g][d4 * 4];
            float4 s1 = *(const float4*)&s_src[2 * g + 1][d4 * 4];
            a0 = fmaf(bv.x, s0.x, a0);
            a0 = fmaf(bv.y, s0.y, a0);
            a0 = fmaf(bv.z, s0.z, a0);
            a0 = fmaf(bv.w, s0.w, a0);
            a1 = fmaf(bv.x, s1.x, a1);
            a1 = fmaf(bv.y, s1.y, a1);
            a1 = fmaf(bv.z, s1.z, a1);
            a1 = fmaf(bv.w, s1.w, a1);
        }
        Wq[(size_t)(r0 + 2 * g) * WQROW + ff * NHS + h * NS + s] = a0;
        Wq[(size_t)(r0 + 2 * g + 1) * WQROW + ff * NHS + h * NS + s] = a1;
    }
}

// ---------------------------------------------------------------------------
// K_QK: sbuf[b,h,l,m] = 0.125 * sum_d src[b,l,h64+d]*src[b,m,h64+d]
// ---------------------------------------------------------------------------
__global__ __launch_bounds__(256) void k_qk(const float* __restrict__ src,
                                            float* __restrict__ sbuf) {
    int mt = blockIdx.x, lt = blockIdx.y, bh = blockIdx.z;
    int b = bh >> 3, h = bh & 7;
    int m0 = mt * 64, l0 = lt * 32;
    int t = threadIdx.x;
    __shared__ float s_A[32][68];
    __shared__ float s_B[64][68];

    #pragma unroll
    for (int i = 0; i < 2; ++i) {
        int idx = i * 256 + t;
        int row = idx >> 4, c4 = idx & 15;
        float4 v = *(const float4*)(src + (size_t)(b * NL + l0 + row) * ND + h * 64 + c4 * 4);
        *(float4*)&s_A[row][c4 * 4] = v;
    }
    {
        int mr = t >> 2, qd = t & 3;
        const float* kp = src + (size_t)(b * NL + m0 + mr) * ND + h * 64 + qd * 16;
        #pragma unroll
        for (int q = 0; q < 4; ++q) {
            float4 v = *(const float4*)(kp + q * 4);
            int d = qd * 16 + q * 4;
            s_B[d + 0][mr] = v.x;
            s_B[d + 1][mr] = v.y;
            s_B[d + 2][mr] = v.z;
            s_B[d + 3][mr] = v.w;
        }
    }
    __syncthreads();

    int tx = t & 15, ty = t >> 4;
    int ty2 = ty * 2;
    float acc[2][4] = {};
    #pragma unroll
    for (int d = 0; d < 64; ++d) {
        float a0 = s_A[ty2][d];
        float a1 = s_A[ty2 + 1][d];
        float4 bv = *(const float4*)&s_B[d][tx * 4];
        acc[0][0] = fmaf(a0, bv.x, acc[0][0]);
        acc[0][1] = fmaf(a0, bv.y, acc[0][1]);
        acc[0][2] = fmaf(a0, bv.z, acc[0][2]);
        acc[0][3] = fmaf(a0, bv.w, acc[0][3]);
        acc[1][0] = fmaf(a1, bv.x, acc[1][0]);
        acc[1][1] = fmaf(a1, bv.y, acc[1][1]);
        acc[1][2] = fmaf(a1, bv.z, acc[1][2]);
        acc[1][3] = fmaf(a1, bv.w, acc[1][3]);
    }
    #pragma unroll
    for (int i = 0; i < 2; ++i) {
        size_t off = ((size_t)bh * NL + l0 + ty2 + i) * NL + m0 + tx * 4;
        *(float4*)(sbuf + off) = make_float4(acc[i][0] * 0.125f, acc[i][1] * 0.125f,
                                             acc[i][2] * 0.125f, acc[i][3] * 0.125f);
    }
}

// ---------------------------------------------------------------------------
// K2a: rp logits + base QK (from sbuf) + softmax for 4 heads of one row.
// ---------------------------------------------------------------------------
__global__ __launch_bounds__(256, 4) void k2a_logits(const float* __restrict__ rel_diss,
                                                     const float* __restrict__ rel_dirs,
                                                     const float* __restrict__ Wq,
                                                     const float* __restrict__ sbuf,
                                                     float* __restrict__ wbuf) {
    int row = blockIdx.x;
    int b = row >> 8;
    int l = row & 255;
    int hg = blockIdx.y;
    int m = threadIdx.x;
    __shared__ float s_wq[64 * 36];
    __shared__ float s_l[4][NL];

    const float* wrow = Wq + (size_t)row * WQROW + hg * 36;
    #pragma unroll
    for (int i = 0; i < 9; ++i) {
        int flat = i * 256 + m;
        int r = flat / 36, c = flat - 36 * r;
        s_wq[flat] = wrow[r * NHS + c];
    }

    float dist = rel_diss[(size_t)row * NL + m];
    const float* dirp = rel_dirs + ((size_t)row * NL + m) * 3;
    float x = dirp[0], y = dirp[1], z = dirp[2];
    float tcl = fminf(fmaxf(dist * 0.1f, 0.f), 1.f);
    float env = 0.5f * (__cosf(3.14159265358979f * tcl) + 1.f);
    int rc = (int)floorf(dist * 6.3f + 0.5f);
    int rlo = min(max(rc - 6, 0), NR - RWIN);
    float sph[NS];
    sph[0] = 0.28209479177387814f * env;
    sph[1] = 0.4886025119029199f * y * env;
    sph[2] = 0.4886025119029199f * z * env;
    sph[3] = 0.4886025119029199f * x * env;
    sph[4] = 1.0925484305920792f * x * y * env;
    sph[5] = 1.0925484305920792f * y * z * env;
    sph[6] = 0.31539156525252005f * (3.f * z * z - 1.f) * env;
    sph[7] = 1.0925484305920792f * x * z * env;
    sph[8] = 0.5462742152960396f * (x * x - y * y) * env;

    __syncthreads();

    float acc[36];
    #pragma unroll
    for (int i = 0; i < 36; ++i) acc[i] = 0.f;
    #pragma unroll 4
    for (int rw = 0; rw < RWIN; ++rw) {
        int r = rlo + rw;
        float df = dist - r * (10.f / 63.f);
        float rbf = __expf(-df * df * 20.48f);
        const float* wp = &s_wq[r * 36];
        #pragma unroll
        for (int q = 0; q < 9; ++q) {
            float4 w = *(const float4*)(wp + q * 4);
            acc[q * 4 + 0] = fmaf(w.x, rbf, acc[q * 4 + 0]);
            acc[q * 4 + 1] = fmaf(w.y, rbf, acc[q * 4 + 1]);
            acc[q * 4 + 2] = fmaf(w.z, rbf, acc[q * 4 + 2]);
            acc[q * 4 + 3] = fmaf(w.w, rbf, acc[q * 4 + 3]);
        }
    }

    const float* sb = sbuf + (((size_t)(b * NH + hg * 4) * NL) + l) * NL + m;
    #pragma unroll
    for (int hh = 0; hh < 4; ++hh) {
        float sc = 0.f;
        #pragma unroll
        for (int s = 0; s < NS; ++s) sc = fmaf(sph[s], acc[hh * NS + s], sc);
        s_l[hh][m] = sc + sb[(size_t)hh * NL * NL];
    }
    __syncthreads();

    int wv = m >> 6, lane = m & 63;
    float v0 = s_l[wv][lane], v1 = s_l[wv][lane + 64];
    float v2 = s_l[wv][lane + 128], v3 = s_l[wv][lane + 192];
    float mx = fmaxf(fmaxf(v0, v1), fmaxf(v2, v3));
    #pragma unroll
    for (int off = 32; off; off >>= 1) mx = fmaxf(mx, __shfl_xor(mx, off, 64));
    float p0 = __expf(v0 - mx), p1 = __expf(v1 - mx);
    float p2 = __expf(v2 - mx), p3 = __expf(v3 - mx);
    float sm = p0 + p1 + p2 + p3;
    #pragma unroll
    for (int off = 32; off; off >>= 1) sm += __shfl_xor(sm, off, 64);
    float inv = 1.f / sm;
    float* wout = wbuf + ((size_t)row * NH + hg * 4 + wv) * NL;
    wout[lane] = p0 * inv;
    wout[lane + 64] = p1 * inv;
    wout[lane + 128] = p2 * inv;
    wout[lane + 192] = p3 * inv;
}

// ---------------------------------------------------------------------------
// K2b: V accumulation + residual + LayerNorm1 -> x1buf (fp32) + x1bf (bf16)
// ---------------------------------------------------------------------------
__global__ __launch_bounds__(256) void k2b_pv(const float* __restrict__ src,
                                              const float* __restrict__ wbuf,
                                              const float* __restrict__ gamma1,
                                              const float* __restrict__ beta1,
                                              float* __restrict__ x1buf,
                                              ushort* __restrict__ x1bf) {
    int row = blockIdx.x;
    int b = row >> 8;
    int t = threadIdx.x;
    __shared__ float s_w[NH][NL];
    __shared__ float s_red[8];

    const float* wrow = wbuf + (size_t)row * (NH * NL);
    #pragma unroll
    for (int i = 0; i < 8; ++i) {
        int flat = i * 256 + t;
        ((float*)s_w)[flat] = wrow[flat];
    }
    __syncthreads();

    int d0 = t * 2;
    int h0 = t >> 5;
    float a0 = 0.f, a1 = 0.f, b0 = 0.f, b1 = 0.f;
    const float* vbase = src + (size_t)b * NL * ND;
    #pragma unroll 2
    for (int mm = 0; mm < NL; mm += 4) {
        float4 w = *(const float4*)&s_w[h0][mm];
        float2 v0 = *(const float2*)(vbase + (size_t)(mm + 0) * ND + d0);
        float2 v1 = *(const float2*)(vbase + (size_t)(mm + 1) * ND + d0);
        float2 v2 = *(const float2*)(vbase + (size_t)(mm + 2) * ND + d0);
        float2 v3 = *(const float2*)(vbase + (size_t)(mm + 3) * ND + d0);
        a0 = fmaf(w.x, v0.x, a0);
        a1 = fmaf(w.x, v0.y, a1);
        b0 = fmaf(w.y, v1.x, b0);
        b1 = fmaf(w.y, v1.y, b1);
        a0 = fmaf(w.z, v2.x, a0);
        a1 = fmaf(w.z, v2.y, a1);
        b0 = fmaf(w.w, v3.x, b0);
        b1 = fmaf(w.w, v3.y, b1);
    }
    a0 += b0;
    a1 += b1;
    const float* qrow = src + (size_t)row * ND;
    float2 s0 = *(const float2*)(qrow + d0);
    float x0 = s0.x + a0, x1v = s0.y + a1;
    float mu = block_sum(x0 + x1v, s_red) * (1.f / 512.f);
    float e0 = x0 - mu, e1 = x1v - mu;
    float var = block_sum(e0 * e0 + e1 * e1, s_red) * (1.f / 512.f);
    float rs = rsqrtf(var + 1e-5f);
    float2 g0 = *(const float2*)(gamma1 + d0), be0 = *(const float2*)(beta1 + d0);
    float o0 = e0 * rs * g0.x + be0.x;
    float o1 = e1 * rs * g0.y + be0.y;
    *(float2*)(x1buf + (size_t)row * ND + d0) = make_float2(o0, o1);
    unsigned pk = (unsigned)f2b(o0) | ((unsigned)f2b(o1) << 16);
    *(unsigned*)(x1bf + (size_t)row * ND + d0) = pk;
}

// ---------------------------------------------------------------------------
// K3 (MFMA): hbf = bf16(leaky_relu(x1bf @ w1t^T + b1))
// A [512][512] bf16 row-major; Bt = w1t [2048][512] bf16 n-major.
// 64x64 tile, 4 waves (wave = 16 rows), K-step 32. grid (32 n, 8 m).
// ---------------------------------------------------------------------------
__global__ __launch_bounds__(256) void k3_mfma(const ushort* __restrict__ A,
                                               const ushort* __restrict__ Bt,
                                               const float* __restrict__ bias,
                                               ushort* __restrict__ C) {
    const int K = 512, N = 2048;
    int n0 = blockIdx.x * 64, m0 = blockIdx.y * 64;
    int t = threadIdx.x;
    int w = t >> 6, l = t & 63;
    __shared__ ushort As[64][40];   // 40-pad: 80B stride, 16B-aligned rows
    __shared__ ushort Bs[64][40];
    f32x4 acc0 = {0.f, 0.f, 0.f, 0.f}, acc1 = acc0, acc2 = acc0, acc3 = acc0;
    int sr = t >> 2, sq = (t & 3) * 8;
    const ushort* Ap = A + (size_t)(m0 + sr) * K + sq;
    const ushort* Bp = Bt + (size_t)(n0 + sr) * K + sq;
    int lr = l & 15, lk = (l >> 4) * 8;
    for (int k0 = 0; k0 < K; k0 += 32) {
        uint4 av = *(const uint4*)(Ap + k0);
        uint4 bv = *(const uint4*)(Bp + k0);
        __syncthreads();
        *(uint4*)&As[sr][sq] = av;
        *(uint4*)&Bs[sr][sq] = bv;
        __syncthreads();
        bf16x8 af = *(const bf16x8*)&As[w * 16 + lr][lk];
        bf16x8 b0 = *(const bf16x8*)&Bs[0 * 16 + lr][lk];
        bf16x8 b1 = *(const bf16x8*)&Bs[1 * 16 + lr][lk];
        bf16x8 b2 = *(const bf16x8*)&Bs[2 * 16 + lr][lk];
        bf16x8 b3 = *(const bf16x8*)&Bs[3 * 16 + lr][lk];
        acc0 = __builtin_amdgcn_mfma_f32_16x16x32_bf16(af, b0, acc0, 0, 0, 0);
        acc1 = __builtin_amdgcn_mfma_f32_16x16x32_bf16(af, b1, acc1, 0, 0, 0);
        acc2 = __builtin_amdgcn_mfma_f32_16x16x32_bf16(af, b2, acc2, 0, 0, 0);
        acc3 = __builtin_amdgcn_mfma_f32_16x16x32_bf16(af, b3, acc3, 0, 0, 0);
    }
    int rbase = m0 + w * 16 + (l >> 4) * 4;
    #pragma unroll
    for (int e = 0; e < 4; ++e) {
        int row = rbase + e;
        float v;
        int col0 = n0 + lr;
        v = acc0[e] + bias[col0];
        C[(size_t)row * N + col0] = f2b(v >= 0.f ? v : 0.01f * v);
        v = acc1[e] + bias[col0 + 16];
        C[(size_t)row * N + col0 + 16] = f2b(v >= 0.f ? v : 0.01f * v);
        v = acc2[e] + bias[col0 + 32];
        C[(size_t)row * N + col0 + 32] = f2b(v >= 0.f ? v : 0.01f * v);
        v = acc3[e] + bias[col0 + 48];
        C[(size_t)row * N + col0 + 48] = f2b(v >= 0.f ? v : 0.01f * v);
    }
}

// ---------------------------------------------------------------------------
// K4 (MFMA): zpart[ks] = hbf[:, ks*512:+512] @ w2t^T chunk -> fp32
// A = hbf [512][2048] bf16; Bt = w2t [512][2048] bf16 n-major.
// 64x64 tile, split-K=4. grid (8 n, 8 m, 4 ks).
// ---------------------------------------------------------------------------
__global__ __launch_bounds__(256) void k4_mfma(const ushort* __restrict__ A,
                                               const ushort* __restrict__ Bt,
                                               float* __restrict__ Cp) {
    const int K = 2048, N = 512;
    int n0 = blockIdx.x * 64, m0 = blockIdx.y * 64;
    int ks = blockIdx.z;
    int t = threadIdx.x;
    int w = t >> 6, l = t & 63;
    __shared__ ushort As[64][40];
    __shared__ ushort Bs[64][40];
    f32x4 acc0 = {0.f, 0.f, 0.f, 0.f}, acc1 = acc0, acc2 = acc0, acc3 = acc0;
    int sr = t >> 2, sq = (t & 3) * 8;
    const ushort* Ap = A + (size_t)(m0 + sr) * K + ks * 512 + sq;
    const ushort* Bp = Bt + (size_t)(n0 + sr) * K + ks * 512 + sq;
    int lr = l & 15, lk = (l >> 4) * 8;
    for (int k0 = 0; k0 < 512; k0 += 32) {
        uint4 av = *(const uint4*)(Ap + k0);
        uint4 bv = *(const uint4*)(Bp + k0);
        __syncthreads();
        *(uint4*)&As[sr][sq] = av;
        *(uint4*)&Bs[sr][sq] = bv;
        __syncthreads();
        bf16x8 af = *(const bf16x8*)&As[w * 16 + lr][lk];
        bf16x8 b0 = *(const bf16x8*)&Bs[0 * 16 + lr][lk];
        bf16x8 b1 = *(const bf16x8*)&Bs[1 * 16 + lr][lk];
        bf16x8 b2 = *(const bf16x8*)&Bs[2 * 16 + lr][lk];
        bf16x8 b3 = *(const bf16x8*)&Bs[3 * 16 + lr][lk];
        acc0 = __builtin_amdgcn_mfma_f32_16x16x32_bf16(af, b0, acc0, 0, 0, 0);
        acc1 = __builtin_amdgcn_mfma_f32_16x16x32_bf16(af, b1, acc1, 0, 0, 0);
        acc2 = __builtin_amdgcn_mfma_f32_16x16x32_bf16(af, b2, acc2, 0, 0, 0);
        acc3 = __builtin_amdgcn_mfma_f32_16x16x32_bf16(af, b3, acc3, 0, 0, 0);
    }
    float* out = Cp + ((size_t)ks << 18);
    int rbase = m0 + w * 16 + (l >> 4) * 4;
    #pragma unroll
    for (int e = 0; e < 4; ++e) {
        int row = rbase + e;
        int col0 = n0 + lr;
        out[(size_t)row * N + col0] = acc0[e];
        out[(size_t)row * N + col0 + 16] = acc1[e];
        out[(size_t)row * N + col0 + 32] = acc2[e];
        out[(size_t)row * N + col0 + 48] = acc3[e];
    }
}

// ---------------------------------------------------------------------------
// K5: z = x1 + b2 + sum_ks zpart[ks]; out = LayerNorm2(z)
// ---------------------------------------------------------------------------
__global__ __launch_bounds__(256) void k5_final(const float* __restrict__ x1buf,
                                                const float* __restrict__ zpart,
                                                const float* __restrict__ b2,
                                                const float* __restrict__ gamma2,
                                                const float* __restrict__ beta2,
                                                float* __restrict__ out) {
    int row = blockIdx.x;
    int t = threadIdx.x;
    int d0 = t * 2;
    __shared__ float s_red[8];
    size_t off = (size_t)row * ND + d0;
    float2 v = *(const float2*)(x1buf + off);
    float2 bb = *(const float2*)(b2 + d0);
    float z0 = v.x + bb.x, z1 = v.y + bb.y;
    #pragma unroll
    for (int ks = 0; ks < 4; ++ks) {
        float2 p = *(const float2*)(zpart + ((size_t)ks << 18) + off);
        z0 += p.x;
        z1 += p.y;
    }
    float mu = block_sum(z0 + z1, s_red) * (1.f / 512.f);
    float e0 = z0 - mu, e1 = z1 - mu;
    float var = block_sum(e0 * e0 + e1 * e1, s_red) * (1.f / 512.f);
    float rs = rsqrtf(var + 1e-5f);
    float2 g = *(const float2*)(gamma2 + d0), be = *(const float2*)(beta2 + d0);
    *(float2*)(out + off) = make_float2(e0 * rs * g.x + be.x, e1 * rs * g.y + be.y);
}

// ---------------------------------------------------------------------------
extern "C" void kernel_launch(void* const* d_in, const int* in_sizes, int n_in,
                              void* d_out, int out_size, void* d_ws, size_t ws_size,
                              hipStream_t stream) {
    const float* src      = (const float*)d_in[0];
    const float* rel_diss = (const float*)d_in[1];
    const float* rel_dirs = (const float*)d_in[2];
    const float* rp_w     = (const float*)d_in[3];
    // d_in[4] = rp_b: constant over softmax axis -> cancels exactly; skipped
    const float* w1  = (const float*)d_in[5];
    const float* b1  = (const float*)d_in[6];
    const float* w2  = (const float*)d_in[7];
    const float* b2  = (const float*)d_in[8];
    const float* g1  = (const float*)d_in[9];
    const float* be1 = (const float*)d_in[10];
    const float* g2  = (const float*)d_in[11];
    const float* be2 = (const float*)d_in[12];
    float* out = (float*)d_out;

    // d_ws is ~256 MiB (observed via harness fill) -> no aliasing needed.
    float* ws = (float*)d_ws;
    float* x1buf = ws;                        // 262144 f
    float* wbuf  = x1buf + 262144;            // 1048576 f (attn weights)
    float* sbuf  = wbuf + 1048576;            // 1048576 f (base QK logits)
    float* zpart = sbuf + 1048576;            // 1048576 f (split-K partials)
    float* Wq    = zpart + 1048576;           // 2359296 f
    ushort* w1t  = (ushort*)(Wq + WQROW * 512);   // 1048576 u16 [2048][512]
    ushort* w2t  = w1t + 1048576;                 // 1048576 u16 [512][2048]
    ushort* x1bf = w2t + 1048576;                 // 262144 u16 [512][512]
    ushort* hbf  = x1bf + 262144;                 // 1048576 u16 [512][2048]

    k_t2b<<<dim3(32, 8), 256, 0, stream>>>(w1, w1t, 512, 2048);
    k_t2b<<<dim3(8, 32), 256, 0, stream>>>(w2, w2t, 2048, 512);
    k1_wq<<<dim3(64, 8), 256, 0, stream>>>(src, rp_w, Wq);
    k_qk<<<dim3(4, 8, 16), 256, 0, stream>>>(src, sbuf);
    k2a_logits<<<dim3(512, 2), 256, 0, stream>>>(rel_diss, rel_dirs, Wq, sbuf, wbuf);
    k2b_pv<<<dim3(512), 256, 0, stream>>>(src, wbuf, g1, be1, x1buf, x1bf);
    k3_mfma<<<dim3(32, 8), 256, 0, stream>>>(x1bf, w1t, b1, hbf);
    k4_mfma<<<dim3(8, 8, 4), 256, 0, stream>>>(hbf, w2t, zpart);
    k5_final<<<dim3(512), 256, 0, stream>>>(x1buf, zpart, b2, g2, be2, out);
}

// Round 9
// 66.652 us; speedup vs baseline: 2.1743x; 1.2695x over previous
//
#include <hip/hip_runtime.h>

// Problem constants
// B=2, L=256, D=512, H=8, Dh=64, NUM_RADIAL=64, N_SPH=9, F=576
#define NB 2
#define NL 256
#define ND 512
#define NH 8
#define NDH 64
#define NR 64
#define NS 9
#define NF 576
#define NHS 72      // NH*NS
#define WQROW 4608  // NR*NHS
#define RWIN 12     // rbf window: terms beyond 5.5*delta < 2e-7 -> negligible

typedef __attribute__((ext_vector_type(8))) short bf16x8;
typedef __attribute__((ext_vector_type(4))) float f32x4;

__device__ __forceinline__ ushort f2b(float f) {   // fp32 -> bf16 RNE
    union { float f; unsigned u; } c; c.f = f;
    unsigned u = c.u;
    return (ushort)((u + 0x7FFF + ((u >> 16) & 1)) >> 16);
}

__device__ __forceinline__ float block_sum4(float v, float* s_red) {
    #pragma unroll
    for (int off = 32; off; off >>= 1) v += __shfl_xor(v, off, 64);
    __syncthreads();
    if ((threadIdx.x & 63) == 0) s_red[threadIdx.x >> 6] = v;
    __syncthreads();
    return s_red[0] + s_red[1] + s_red[2] + s_red[3];
}

__device__ __forceinline__ float block_sum8(float v, float* s_red) {
    #pragma unroll
    for (int off = 32; off; off >>= 1) v += __shfl_xor(v, off, 64);
    __syncthreads();
    if ((threadIdx.x & 63) == 0) s_red[threadIdx.x >> 6] = v;
    __syncthreads();
    return ((s_red[0] + s_red[1]) + (s_red[2] + s_red[3])) +
           ((s_red[4] + s_red[5]) + (s_red[6] + s_red[7]));
}

// ---------------------------------------------------------------------------
// K_PRE: union of 4 independent pre-kernels, one dispatch (1536 blocks):
//   [0,256)    t2b(w1)  [256,512) t2b(w2)  [512,1024) k1  [1024,1536) k_qk
// ---------------------------------------------------------------------------
__global__ __launch_bounds__(256, 4) void k_pre(const float* __restrict__ src,
                                                const float* __restrict__ rp_w,
                                                const float* __restrict__ w1,
                                                const float* __restrict__ w2,
                                                float* __restrict__ Wq,
                                                float* __restrict__ sbuf,
                                                ushort* __restrict__ w1t,
                                                ushort* __restrict__ w2t) {
    __shared__ __align__(16) char raw[26368];
    int bi = blockIdx.x;
    int t = threadIdx.x;

    if (bi < 512) {
        // ---- transpose + bf16 convert: out[n][k] = bf16(in[k][n]) ----
        const float* in;
        ushort* out;
        int K, N, bx, by;
        if (bi < 256) { in = w1; out = w1t; K = 512; N = 2048; bx = bi & 31; by = bi >> 5; }
        else { int id = bi - 256; in = w2; out = w2t; K = 2048; N = 512; bx = id & 7; by = id >> 3; }
        float (*tile)[65] = (float(*)[65])raw;
        int n0 = bx * 64, k0 = by * 64;
        int r = t >> 4, c4 = (t & 15) * 4;
        #pragma unroll
        for (int i = 0; i < 4; ++i) {
            int kk = i * 16 + r;
            float4 v = *(const float4*)(in + (size_t)(k0 + kk) * N + n0 + c4);
            tile[kk][c4 + 0] = v.x;
            tile[kk][c4 + 1] = v.y;
            tile[kk][c4 + 2] = v.z;
            tile[kk][c4 + 3] = v.w;
        }
        __syncthreads();
        int rr = t >> 2, cq = (t & 3) * 16;
        ushort buf[16];
        #pragma unroll
        for (int j = 0; j < 16; ++j) buf[j] = f2b(tile[cq + j][rr]);
        ushort* op = out + (size_t)(n0 + rr) * K + k0 + cq;
        *(uint4*)(op) = *(uint4*)&buf[0];
        *(uint4*)(op + 8) = *(uint4*)&buf[8];
    } else if (bi < 1024) {
        // ---- K1: Wq[row][r*72 + h*9+s] ----
        int id = bi - 512;
        int rt = id & 63, h = id >> 6;
        float (*s_src)[64] = (float(*)[64])raw;          // 2 KB
        float* s_B = (float*)(raw + 2048);               // 16 KB
        int r0 = rt * 8;
        {
            int sr = t >> 5;
            int sc = (t & 31) * 2;
            *(float2*)&s_src[sr][sc] =
                *(const float2*)(src + (size_t)(r0 + sr) * ND + h * 64 + sc);
        }
        int ff = t & 63;
        int g  = t >> 6;
        int lr = t >> 2;
        int lq = t & 3;
        const float* bsrc = rp_w + h * 64;
        #pragma unroll 1
        for (int s = 0; s < NS; ++s) {
            __syncthreads();
            #pragma unroll
            for (int i = 0; i < 4; ++i) {
                int slot = i * 4 + lq;
                float4 v = *(const float4*)(bsrc + (size_t)(s * 64 + lr) * ND + slot * 4);
                int sw = slot ^ (lr & 7);
                *(float4*)&s_B[lr * 64 + sw * 4] = v;
            }
            __syncthreads();
            float a0 = 0.f, a1 = 0.f;
            #pragma unroll
            for (int d4 = 0; d4 < 16; ++d4) {
                int sw = d4 ^ (ff & 7);
                float4 bv = *(const float4*)&s_B[ff * 64 + sw * 4];
                float4 s0 = *(const float4*)&s_src[2 * g][d4 * 4];
                float4 s1 = *(const float4*)&s_src[2 * g + 1][d4 * 4];
                a0 = fmaf(bv.x, s0.x, a0);
                a0 = fmaf(bv.y, s0.y, a0);
                a0 = fmaf(bv.z, s0.z, a0);
                a0 = fmaf(bv.w, s0.w, a0);
                a1 = fmaf(bv.x, s1.x, a1);
                a1 = fmaf(bv.y, s1.y, a1);
                a1 = fmaf(bv.z, s1.z, a1);
                a1 = fmaf(bv.w, s1.w, a1);
            }
            Wq[(size_t)(r0 + 2 * g) * WQROW + ff * NHS + h * NS + s] = a0;
            Wq[(size_t)(r0 + 2 * g + 1) * WQROW + ff * NHS + h * NS + s] = a1;
        }
    } else {
        // ---- K_QK: sbuf[b,h,l,m] = 0.125 * q.k ----
        int id = bi - 1024;
        int mt = id & 3, lt = (id >> 2) & 7, bh = id >> 5;
        int b = bh >> 3, h = bh & 7;
        int m0 = mt * 64, l0 = lt * 32;
        float (*s_A)[68] = (float(*)[68])raw;            // 8.7 KB
        float (*s_B)[68] = (float(*)[68])(raw + 8704);   // 17.4 KB
        #pragma unroll
        for (int i = 0; i < 2; ++i) {
            int idx = i * 256 + t;
            int row = idx >> 4, c4 = idx & 15;
            float4 v = *(const float4*)(src + (size_t)(b * NL + l0 + row) * ND + h * 64 + c4 * 4);
            *(float4*)&s_A[row][c4 * 4] = v;
        }
        {
            int mr = t >> 2, qd = t & 3;
            const float* kp = src + (size_t)(b * NL + m0 + mr) * ND + h * 64 + qd * 16;
            #pragma unroll
            for (int q = 0; q < 4; ++q) {
                float4 v = *(const float4*)(kp + q * 4);
                int d = qd * 16 + q * 4;
                s_B[d + 0][mr] = v.x;
                s_B[d + 1][mr] = v.y;
                s_B[d + 2][mr] = v.z;
                s_B[d + 3][mr] = v.w;
            }
        }
        __syncthreads();
        int tx = t & 15, ty = t >> 4;
        int ty2 = ty * 2;
        float acc[2][4] = {};
        #pragma unroll
        for (int d = 0; d < 64; ++d) {
            float a0 = s_A[ty2][d];
            float a1 = s_A[ty2 + 1][d];
            float4 bv = *(const float4*)&s_B[d][tx * 4];
            acc[0][0] = fmaf(a0, bv.x, acc[0][0]);
            acc[0][1] = fmaf(a0, bv.y, acc[0][1]);
            acc[0][2] = fmaf(a0, bv.z, acc[0][2]);
            acc[0][3] = fmaf(a0, bv.w, acc[0][3]);
            acc[1][0] = fmaf(a1, bv.x, acc[1][0]);
            acc[1][1] = fmaf(a1, bv.y, acc[1][1]);
            acc[1][2] = fmaf(a1, bv.z, acc[1][2]);
            acc[1][3] = fmaf(a1, bv.w, acc[1][3]);
        }
        #pragma unroll
        for (int i = 0; i < 2; ++i) {
            size_t off = ((size_t)bh * NL + l0 + ty2 + i) * NL + m0 + tx * 4;
            *(float4*)(sbuf + off) = make_float4(acc[i][0] * 0.125f, acc[i][1] * 0.125f,
                                                 acc[i][2] * 0.125f, acc[i][3] * 0.125f);
        }
    }
}

// ---------------------------------------------------------------------------
// K2_FUSED: per row (512 threads): rp logits (windowed contraction, thread =
// (m, head-group)) + base QK from sbuf + per-wave softmax (wave = head) +
// PV (thread = d) + residual + LayerNorm1 -> x1buf/x1bf. No wbuf round-trip.
// ---------------------------------------------------------------------------
__global__ __launch_bounds__(512, 4) void k2_fused(const float* __restrict__ src,
                                                   const float* __restrict__ rel_diss,
                                                   const float* __restrict__ rel_dirs,
                                                   const float* __restrict__ Wq,
                                                   const float* __restrict__ sbuf,
                                                   const float* __restrict__ gamma1,
                                                   const float* __restrict__ beta1,
                                                   float* __restrict__ x1buf,
                                                   ushort* __restrict__ x1bf) {
    int row = blockIdx.x;      // b*256 + l
    int b = row >> 8;
    int l = row & 255;
    int t = threadIdx.x;
    int m = t & 255;           // key index
    int hg = t >> 8;           // head group 0/1 (heads hg*4..hg*4+3)
    __shared__ float s_wq[64][76];   // 19.5 KB (stride 76: 8 bank-quad starts)
    __shared__ float s_l[NH][NL];    // 8 KB logits -> weights
    __shared__ float s_red[8];

    // --- stage full Wq row [r][72] into [64][76] ---
    const float* wrow = Wq + (size_t)row * WQROW;
    #pragma unroll
    for (int i = 0; i < 9; ++i) {
        int flat = i * 512 + t;          // 0..4607
        int r = flat / 72, c = flat - 72 * r;
        s_wq[r][c] = wrow[flat];
    }

    // --- rbf window + spherical harmonics (env folded) for (l, m) ---
    float dist = rel_diss[(size_t)row * NL + m];
    const float* dirp = rel_dirs + ((size_t)row * NL + m) * 3;
    float x = dirp[0], y = dirp[1], z = dirp[2];
    float tcl = fminf(fmaxf(dist * 0.1f, 0.f), 1.f);
    float env = 0.5f * (__cosf(3.14159265358979f * tcl) + 1.f);
    int rc = (int)floorf(dist * 6.3f + 0.5f);
    int rlo = min(max(rc - 6, 0), NR - RWIN);
    float sph[NS];
    sph[0] = 0.28209479177387814f * env;
    sph[1] = 0.4886025119029199f * y * env;
    sph[2] = 0.4886025119029199f * z * env;
    sph[3] = 0.4886025119029199f * x * env;
    sph[4] = 1.0925484305920792f * x * y * env;
    sph[5] = 1.0925484305920792f * y * z * env;
    sph[6] = 0.31539156525252005f * (3.f * z * z - 1.f) * env;
    sph[7] = 1.0925484305920792f * x * z * env;
    sph[8] = 0.5462742152960396f * (x * x - y * y) * env;

    __syncthreads();

    // --- rp contraction over the 12-r window, 36 accumulators (4 heads) ---
    float acc[36];
    #pragma unroll
    for (int i = 0; i < 36; ++i) acc[i] = 0.f;
    #pragma unroll 4
    for (int rw = 0; rw < RWIN; ++rw) {
        int r = rlo + rw;
        float df = dist - r * (10.f / 63.f);
        float rbf = __expf(-df * df * 20.48f);
        const float* wp = &s_wq[r][hg * 36];
        #pragma unroll
        for (int q = 0; q < 9; ++q) {
            float4 w = *(const float4*)(wp + q * 4);
            acc[q * 4 + 0] = fmaf(w.x, rbf, acc[q * 4 + 0]);
            acc[q * 4 + 1] = fmaf(w.y, rbf, acc[q * 4 + 1]);
            acc[q * 4 + 2] = fmaf(w.z, rbf, acc[q * 4 + 2]);
            acc[q * 4 + 3] = fmaf(w.w, rbf, acc[q * 4 + 3]);
        }
    }

    // --- sph reduce + base QK (coalesced) -> logits ---
    const float* sb = sbuf + (((size_t)(b * NH + hg * 4) * NL) + l) * NL + m;
    #pragma unroll
    for (int hh = 0; hh < 4; ++hh) {
        float sc = 0.f;
        #pragma unroll
        for (int s = 0; s < NS; ++s) sc = fmaf(sph[s], acc[hh * NS + s], sc);
        s_l[hg * 4 + hh][m] = sc + sb[(size_t)hh * NL * NL];
    }
    __syncthreads();

    // --- softmax: wave w (of 8) handles head w ---
    int wv = t >> 6, lane = t & 63;
    {
        float v0 = s_l[wv][lane], v1 = s_l[wv][lane + 64];
        float v2 = s_l[wv][lane + 128], v3 = s_l[wv][lane + 192];
        float mx = fmaxf(fmaxf(v0, v1), fmaxf(v2, v3));
        #pragma unroll
        for (int off = 32; off; off >>= 1) mx = fmaxf(mx, __shfl_xor(mx, off, 64));
        float p0 = __expf(v0 - mx), p1 = __expf(v1 - mx);
        float p2 = __expf(v2 - mx), p3 = __expf(v3 - mx);
        float sm = p0 + p1 + p2 + p3;
        #pragma unroll
        for (int off = 32; off; off >>= 1) sm += __shfl_xor(sm, off, 64);
        float inv = 1.f / sm;
        s_l[wv][lane] = p0 * inv;
        s_l[wv][lane + 64] = p1 * inv;
        s_l[wv][lane + 128] = p2 * inv;
        s_l[wv][lane + 192] = p3 * inv;
    }
    __syncthreads();

    // --- PV: thread t owns dim d = t; head = d>>6 = wave -> broadcast reads ---
    int d = t;
    int h0 = t >> 6;
    float a0 = 0.f, a1 = 0.f, a2 = 0.f, a3 = 0.f;
    const float* vbase = src + (size_t)b * NL * ND + d;
    #pragma unroll 2
    for (int mm = 0; mm < NL; mm += 4) {
        float4 wv4 = *(const float4*)&s_l[h0][mm];   // wave-uniform -> broadcast
        a0 = fmaf(wv4.x, vbase[(size_t)(mm + 0) * ND], a0);
        a1 = fmaf(wv4.y, vbase[(size_t)(mm + 1) * ND], a1);
        a2 = fmaf(wv4.z, vbase[(size_t)(mm + 2) * ND], a2);
        a3 = fmaf(wv4.w, vbase[(size_t)(mm + 3) * ND], a3);
    }
    float av = (a0 + a1) + (a2 + a3);

    // --- residual + LayerNorm1 (1 element per thread, 8-wave reduction) ---
    float x0 = src[(size_t)row * ND + d] + av;
    float mu = block_sum8(x0, s_red) * (1.f / 512.f);
    float e0 = x0 - mu;
    float var = block_sum8(e0 * e0, s_red) * (1.f / 512.f);
    float rs = rsqrtf(var + 1e-5f);
    float o = e0 * rs * gamma1[d] + beta1[d];
    x1buf[(size_t)row * ND + d] = o;
    x1bf[(size_t)row * ND + d] = f2b(o);
}

// ---------------------------------------------------------------------------
// K3 (MFMA): hbf = bf16(leaky_relu(x1bf @ w1t^T + b1))
// ---------------------------------------------------------------------------
__global__ __launch_bounds__(256) void k3_mfma(const ushort* __restrict__ A,
                                               const ushort* __restrict__ Bt,
                                               const float* __restrict__ bias,
                                               ushort* __restrict__ C) {
    const int K = 512, N = 2048;
    int n0 = blockIdx.x * 64, m0 = blockIdx.y * 64;
    int t = threadIdx.x;
    int w = t >> 6, l = t & 63;
    __shared__ ushort As[64][40];
    __shared__ ushort Bs[64][40];
    f32x4 acc0 = {0.f, 0.f, 0.f, 0.f}, acc1 = acc0, acc2 = acc0, acc3 = acc0;
    int sr = t >> 2, sq = (t & 3) * 8;
    const ushort* Ap = A + (size_t)(m0 + sr) * K + sq;
    const ushort* Bp = Bt + (size_t)(n0 + sr) * K + sq;
    int lr = l & 15, lk = (l >> 4) * 8;
    for (int k0 = 0; k0 < K; k0 += 32) {
        uint4 av = *(const uint4*)(Ap + k0);
        uint4 bv = *(const uint4*)(Bp + k0);
        __syncthreads();
        *(uint4*)&As[sr][sq] = av;
        *(uint4*)&Bs[sr][sq] = bv;
        __syncthreads();
        bf16x8 af = *(const bf16x8*)&As[w * 16 + lr][lk];
        bf16x8 b0 = *(const bf16x8*)&Bs[0 * 16 + lr][lk];
        bf16x8 b1 = *(const bf16x8*)&Bs[1 * 16 + lr][lk];
        bf16x8 b2 = *(const bf16x8*)&Bs[2 * 16 + lr][lk];
        bf16x8 b3 = *(const bf16x8*)&Bs[3 * 16 + lr][lk];
        acc0 = __builtin_amdgcn_mfma_f32_16x16x32_bf16(af, b0, acc0, 0, 0, 0);
        acc1 = __builtin_amdgcn_mfma_f32_16x16x32_bf16(af, b1, acc1, 0, 0, 0);
        acc2 = __builtin_amdgcn_mfma_f32_16x16x32_bf16(af, b2, acc2, 0, 0, 0);
        acc3 = __builtin_amdgcn_mfma_f32_16x16x32_bf16(af, b3, acc3, 0, 0, 0);
    }
    int rbase = m0 + w * 16 + (l >> 4) * 4;
    #pragma unroll
    for (int e = 0; e < 4; ++e) {
        int row = rbase + e;
        float v;
        int col0 = n0 + lr;
        v = acc0[e] + bias[col0];
        C[(size_t)row * N + col0] = f2b(v >= 0.f ? v : 0.01f * v);
        v = acc1[e] + bias[col0 + 16];
        C[(size_t)row * N + col0 + 16] = f2b(v >= 0.f ? v : 0.01f * v);
        v = acc2[e] + bias[col0 + 32];
        C[(size_t)row * N + col0 + 32] = f2b(v >= 0.f ? v : 0.01f * v);
        v = acc3[e] + bias[col0 + 48];
        C[(size_t)row * N + col0 + 48] = f2b(v >= 0.f ? v : 0.01f * v);
    }
}

// ---------------------------------------------------------------------------
// K4 (MFMA): zpart[ks] = hbf[:, ks*512:+512] @ w2t^T chunk -> fp32
// ---------------------------------------------------------------------------
__global__ __launch_bounds__(256) void k4_mfma(const ushort* __restrict__ A,
                                               const ushort* __restrict__ Bt,
                                               float* __restrict__ Cp) {
    const int K = 2048, N = 512;
    int n0 = blockIdx.x * 64, m0 = blockIdx.y * 64;
    int ks = blockIdx.z;
    int t = threadIdx.x;
    int w = t >> 6, l = t & 63;
    __shared__ ushort As[64][40];
    __shared__ ushort Bs[64][40];
    f32x4 acc0 = {0.f, 0.f, 0.f, 0.f}, acc1 = acc0, acc2 = acc0, acc3 = acc0;
    int sr = t >> 2, sq = (t & 3) * 8;
    const ushort* Ap = A + (size_t)(m0 + sr) * K + ks * 512 + sq;
    const ushort* Bp = Bt + (size_t)(n0 + sr) * K + ks * 512 + sq;
    int lr = l & 15, lk = (l >> 4) * 8;
    for (int k0 = 0; k0 < 512; k0 += 32) {
        uint4 av = *(const uint4*)(Ap + k0);
        uint4 bv = *(const uint4*)(Bp + k0);
        __syncthreads();
        *(uint4*)&As[sr][sq] = av;
        *(uint4*)&Bs[sr][sq] = bv;
        __syncthreads();
        bf16x8 af = *(const bf16x8*)&As[w * 16 + lr][lk];
        bf16x8 b0 = *(const bf16x8*)&Bs[0 * 16 + lr][lk];
        bf16x8 b1 = *(const bf16x8*)&Bs[1 * 16 + lr][lk];
        bf16x8 b2 = *(const bf16x8*)&Bs[2 * 16 + lr][lk];
        bf16x8 b3 = *(const bf16x8*)&Bs[3 * 16 + lr][lk];
        acc0 = __builtin_amdgcn_mfma_f32_16x16x32_bf16(af, b0, acc0, 0, 0, 0);
        acc1 = __builtin_amdgcn_mfma_f32_16x16x32_bf16(af, b1, acc1, 0, 0, 0);
        acc2 = __builtin_amdgcn_mfma_f32_16x16x32_bf16(af, b2, acc2, 0, 0, 0);
        acc3 = __builtin_amdgcn_mfma_f32_16x16x32_bf16(af, b3, acc3, 0, 0, 0);
    }
    float* out = Cp + ((size_t)ks << 18);
    int rbase = m0 + w * 16 + (l >> 4) * 4;
    #pragma unroll
    for (int e = 0; e < 4; ++e) {
        int row = rbase + e;
        int col0 = n0 + lr;
        out[(size_t)row * N + col0] = acc0[e];
        out[(size_t)row * N + col0 + 16] = acc1[e];
        out[(size_t)row * N + col0 + 32] = acc2[e];
        out[(size_t)row * N + col0 + 48] = acc3[e];
    }
}

// ---------------------------------------------------------------------------
// K5: z = x1 + b2 + sum_ks zpart[ks]; out = LayerNorm2(z)
// ---------------------------------------------------------------------------
__global__ __launch_bounds__(256) void k5_final(const float* __restrict__ x1buf,
                                                const float* __restrict__ zpart,
                                                const float* __restrict__ b2,
                                                const float* __restrict__ gamma2,
                                                const float* __restrict__ beta2,
                                                float* __restrict__ out) {
    int row = blockIdx.x;
    int t = threadIdx.x;
    int d0 = t * 2;
    __shared__ float s_red[8];
    size_t off = (size_t)row * ND + d0;
    float2 v = *(const float2*)(x1buf + off);
    float2 bb = *(const float2*)(b2 + d0);
    float z0 = v.x + bb.x, z1 = v.y + bb.y;
    #pragma unroll
    for (int ks = 0; ks < 4; ++ks) {
        float2 p = *(const float2*)(zpart + ((size_t)ks << 18) + off);
        z0 += p.x;
        z1 += p.y;
    }
    float mu = block_sum4(z0 + z1, s_red) * (1.f / 512.f);
    float e0 = z0 - mu, e1 = z1 - mu;
    float var = block_sum4(e0 * e0 + e1 * e1, s_red) * (1.f / 512.f);
    float rs = rsqrtf(var + 1e-5f);
    float2 g = *(const float2*)(gamma2 + d0), be = *(const float2*)(beta2 + d0);
    *(float2*)(out + off) = make_float2(e0 * rs * g.x + be.x, e1 * rs * g.y + be.y);
}

// ---------------------------------------------------------------------------
extern "C" void kernel_launch(void* const* d_in, const int* in_sizes, int n_in,
                              void* d_out, int out_size, void* d_ws, size_t ws_size,
                              hipStream_t stream) {
    const float* src      = (const float*)d_in[0];
    const float* rel_diss = (const float*)d_in[1];
    const float* rel_dirs = (const float*)d_in[2];
    const float* rp_w     = (const float*)d_in[3];
    // d_in[4] = rp_b: constant over softmax axis -> cancels exactly; skipped
    const float* w1  = (const float*)d_in[5];
    const float* b1  = (const float*)d_in[6];
    const float* w2  = (const float*)d_in[7];
    const float* b2  = (const float*)d_in[8];
    const float* g1  = (const float*)d_in[9];
    const float* be1 = (const float*)d_in[10];
    const float* g2  = (const float*)d_in[11];
    const float* be2 = (const float*)d_in[12];
    float* out = (float*)d_out;

    float* ws = (float*)d_ws;
    float* x1buf = ws;                        // 262144 f
    float* sbuf  = x1buf + 262144;            // 1048576 f (base QK logits)
    float* zpart = sbuf + 1048576;            // 1048576 f (split-K partials)
    float* Wq    = zpart + 1048576;           // 2359296 f
    ushort* w1t  = (ushort*)(Wq + WQROW * 512);   // 1048576 u16 [2048][512]
    ushort* w2t  = w1t + 1048576;                 // 1048576 u16 [512][2048]
    ushort* x1bf = w2t + 1048576;                 // 262144 u16 [512][512]
    ushort* hbf  = x1bf + 262144;                 // 1048576 u16 [512][2048]

    k_pre<<<1536, 256, 0, stream>>>(src, rp_w, w1, w2, Wq, sbuf, w1t, w2t);
    k2_fused<<<512, 512, 0, stream>>>(src, rel_diss, rel_dirs, Wq, sbuf,
                                      g1, be1, x1buf, x1bf);
    k3_mfma<<<dim3(32, 8), 256, 0, stream>>>(x1bf, w1t, b1, hbf);
    k4_mfma<<<dim3(8, 8, 4), 256, 0, stream>>>(hbf, w2t, zpart);
    k5_final<<<512, 256, 0, stream>>>(x1buf, zpart, b2, g2, be2, out);
}